// Round 16
// baseline (182.351 us; speedup 1.0000x reference)
//
#include <hip/hip_runtime.h>
#include <cstdint>
#include <cstddef>

#define NPTS 8192
#define NBATCH 4
#define KNN 10
#define NPAIR 45
#define TILE 512
#define MARGIN 12
#define QSZ 96
#define DRAIN_AT 16
#define EPSD 1e-6
#define GRID 14
#define NCELL (GRID*GRID*GRID)
#define HCELL 0.7f
#define ORG (-4.9f)

__device__ __constant__ int dCOMB_A[NPAIR] = {
  0,0,0,0,0,0,0,0,0, 1,1,1,1,1,1,1,1, 2,2,2,2,2,2,2,
  3,3,3,3,3,3, 4,4,4,4,4, 5,5,5,5, 6,6,6, 7,7, 8};
__device__ __constant__ int dCOMB_B[NPAIR] = {
  1,2,3,4,5,6,7,8,9, 2,3,4,5,6,7,8,9, 3,4,5,6,7,8,9,
  4,5,6,7,8,9, 5,6,7,8,9, 6,7,8,9, 7,8,9, 8,9, 9};

__device__ __forceinline__ void cell_coords(float x, float y, float z,
                                            int& cx, int& cy, int& cz) {
  cx = (int)floorf((x - ORG) * (1.0f / HCELL));
  cy = (int)floorf((y - ORG) * (1.0f / HCELL));
  cz = (int)floorf((z - ORG) * (1.0f / HCELL));
  cx = min(max(cx, 0), GRID - 1);
  cy = min(max(cy, 0), GRID - 1);
  cz = min(max(cz, 0), GRID - 1);
}

__device__ __forceinline__ uint64_t shfl_xor64(uint64_t v, int m) {
  uint32_t lo = (uint32_t)__shfl_xor((int)(uint32_t)v, m, 64);
  uint32_t hi = (uint32_t)__shfl_xor((int)(uint32_t)(v >> 32), m, 64);
  return ((uint64_t)hi << 32) | lo;
}
__device__ __forceinline__ uint64_t shfl_up64(uint64_t v, int d) {
  uint32_t lo = (uint32_t)__shfl_up((int)(uint32_t)v, d, 64);
  uint32_t hi = (uint32_t)__shfl_up((int)(uint32_t)(v >> 32), d, 64);
  return ((uint64_t)hi << 32) | lo;
}
__device__ __forceinline__ uint64_t shfl64(uint64_t v, int src) {
  uint32_t lo = (uint32_t)__shfl((int)(uint32_t)v, src, 64);
  uint32_t hi = (uint32_t)__shfl((int)(uint32_t)(v >> 32), src, 64);
  return ((uint64_t)hi << 32) | lo;
}

// ---------------- fused grid build: one block per batch (unchanged R15) ----------------
__global__ __launch_bounds__(1024) void grid_build(const float* __restrict__ src,
                                                   float4* __restrict__ pts,
                                                   uint32_t* __restrict__ oidx,
                                                   uint32_t* __restrict__ cstart) {
  __shared__ uint32_t scnt[NCELL];
  __shared__ uint32_t swv[16];
  const int b = blockIdx.x;
  const int tid = threadIdx.x, lane = tid & 63, wid = tid >> 6;
  const float* __restrict__ sb = src + (size_t)b * 3 * NPTS;

  for (int i = tid; i < NCELL; i += 1024) scnt[i] = 0;
  __syncthreads();

  float px[8], py[8], pz[8];
  int pc[8];
#pragma unroll
  for (int k = 0; k < 8; ++k) {
    int p = tid + k * 1024;
    float x = sb[p], y = sb[NPTS + p], z = sb[2 * NPTS + p];
    px[k] = x; py[k] = y; pz[k] = z;
    int cx, cy, cz;
    cell_coords(x, y, z, cx, cy, cz);
    pc[k] = ((cz * GRID) + cy) * GRID + cx;
    atomicAdd(&scnt[pc[k]], 1u);
  }
  __syncthreads();

  const int i0 = tid * 4;
  uint32_t v[4], ts = 0;
#pragma unroll
  for (int k = 0; k < 4; ++k) {
    v[k] = (i0 + k < NCELL) ? scnt[i0 + k] : 0u;
    ts += v[k];
  }
  uint32_t x = ts;
#pragma unroll
  for (int off = 1; off < 64; off <<= 1) {
    uint32_t y = __shfl_up(x, off, 64);
    if (lane >= off) x += y;
  }
  if (lane == 63) swv[wid] = x;
  __syncthreads();
  uint32_t wpre = 0, bsum = 0;
  for (int w = 0; w < 16; ++w) { uint32_t s = swv[w]; bsum += s; if (w < wid) wpre += s; }
  uint32_t excl = wpre + (x - ts);
#pragma unroll
  for (int k = 0; k < 4; ++k) {
    if (i0 + k < NCELL) {
      cstart[b * (NCELL + 1) + i0 + k] = excl;
      scnt[i0 + k] = excl;
      excl += v[k];
    }
  }
  if (tid == 0) cstart[b * (NCELL + 1) + NCELL] = bsum;
  __syncthreads();

#pragma unroll
  for (int k = 0; k < 8; ++k) {
    uint32_t pos = atomicAdd(&scnt[pc[k]], 1u);
    pts[(b << 13) + pos]  = make_float4(px[k], py[k], pz[k],
                                        px[k] * px[k] + py[k] * py[k] + pz[k] * pz[k]);
    oidx[(b << 13) + pos] = (uint32_t)(tid + k * 1024);
  }
}

// ---------------- main: register-resident sorted top-12, no LDS queue ----------------
__global__ __launch_bounds__(256) void gfm_grid(const float* __restrict__ src,
                                                const float* __restrict__ tgt,
                                                const float4* __restrict__ pts,
                                                const uint32_t* __restrict__ oidx,
                                                const uint32_t* __restrict__ cstart,
                                                float* __restrict__ mean_out) {
  __shared__ double lsA[4][NPAIR];
  __shared__ double lsB[4][NPAIR];
  __shared__ double smed[4];
  __shared__ double ssum[4][KNN];
  __shared__ double rd2[4][MARGIN];
  __shared__ int    rid[4][MARGIN];
  __shared__ int    snbr[4][KNN];

  const int tid  = threadIdx.x;
  const int wv   = tid >> 6;
  const int lane = tid & 63;
  const int b    = blockIdx.x >> 11;
  const int pos  = ((blockIdx.x & 2047) << 2) | wv;   // cell-sorted position

  const float* __restrict__ sb = src + (size_t)b * 3 * NPTS;
  const float* __restrict__ tb = tgt + (size_t)b * 3 * NPTS;
  const float4* __restrict__ ppts = pts + ((size_t)b << 13);
  const uint32_t* __restrict__ poid = oidx + ((size_t)b << 13);
  const uint32_t* __restrict__ cs = cstart + (size_t)b * (NCELL + 1);

  const float4 q4 = ppts[pos];
  const int n = (int)poid[pos];
  const float xnf = q4.x, ynf = q4.y, znf = q4.z;
  const float sqnf = q4.w;

  int qcx, qcy, qcz;
  cell_coords(xnf, ynf, znf, qcx, qcy, qcz);
  float lox = ORG + qcx * HCELL, loy = ORG + qcy * HCELL, loz = ORG + qcz * HCELL;
  float dqx = fmaxf(fmaxf(lox - xnf, xnf - (lox + HCELL)), 0.0f);
  float dqy = fmaxf(fmaxf(loy - ynf, ynf - (loy + HCELL)), 0.0f);
  float dqz = fmaxf(fmaxf(loz - znf, znf - (loz + HCELL)), 0.0f);
  const float deltaq = sqrtf(dqx * dqx + dqy * dqy + dqz * dqz);

  // running top-12: lanes 0..11 hold sorted ascending u64 keys in registers
  uint64_t stp_reg = ~0ull;
  float tau_f = __builtin_inff();
  bool boot = false;

  auto upd_tau = [&]() {
    uint64_t t11 = shfl64(stp_reg, MARGIN - 1);
    uint32_t tb32 = (uint32_t)(t11 >> 32);
    tau_f = (tb32 == 0xFFFFFFFFu) ? __builtin_inff() : __uint_as_float(tb32);
  };

  auto scan_range = [&](int cy, int cz, int cx0, int cx1) {
    if (cy < 0 || cy >= GRID || cz < 0 || cz >= GRID) return;
    cx0 = max(cx0, 0); cx1 = min(cx1, GRID - 1);
    if (cx0 > cx1) return;
    float bx0 = ORG + cx0 * HCELL, bx1 = ORG + (cx1 + 1) * HCELL;
    float by0 = ORG + cy * HCELL,  by1 = by0 + HCELL;
    float bz0 = ORG + cz * HCELL,  bz1 = bz0 + HCELL;
    float ddx = fmaxf(fmaxf(bx0 - xnf, xnf - bx1), 0.0f);
    float ddy = fmaxf(fmaxf(by0 - ynf, ynf - by1), 0.0f);
    float ddz = fmaxf(fmaxf(bz0 - znf, znf - bz1), 0.0f);
    float rowmin = ddx * ddx + ddy * ddy + ddz * ddz;
    if (rowmin > tau_f * 1.001f + 1e-5f) return;   // inf-safe, conservative
    uint32_t c0 = (uint32_t)(((cz * GRID) + cy) * GRID + cx0);
    uint32_t st = cs[c0];
    uint32_t en = cs[c0 + (uint32_t)(cx1 - cx0) + 1];
    for (uint32_t base = st; base < en; base += 64) {
      uint32_t pp = base + (uint32_t)lane;
      bool act = pp < en;
      bool pred = false;
      uint64_t key = ~0ull;
      if (act) {
        float4 c4 = ppts[pp];
        float dot = fmaf(xnf, c4.x, fmaf(ynf, c4.y, znf * c4.z));
        float d2 = fmaxf(fmaf(-2.0f, dot, sqnf + c4.w), 0.0f);
        pred = d2 <= tau_f;
        key = ((uint64_t)__float_as_uint(d2) << 32) | (uint64_t)poid[pp];
      }
      if (!boot) {
        // bitonic sort 64 lanes ascending; lanes 0..11 become exact top-12
        uint64_t kk = pred ? key : ~0ull;
#pragma unroll
        for (int k = 2; k <= 64; k <<= 1) {
#pragma unroll
          for (int j = k >> 1; j > 0; j >>= 1) {
            uint64_t partner = shfl_xor64(kk, j);
            bool tmin = (((lane & k) == 0) == ((lane & j) == 0));
            uint64_t mn = (kk < partner) ? kk : partner;
            uint64_t mx = (kk < partner) ? partner : kk;
            kk = tmin ? mn : mx;
          }
        }
        stp_reg = (lane < MARGIN) ? kk : ~0ull;
        boot = true;
        upd_tau();
        continue;
      }
      uint64_t m2 = __ballot(pred);
      if (m2) {                       // wave-uniform
        do {
          int l = __ffsll((unsigned long long)m2) - 1;
          m2 &= m2 - 1;
          uint64_t bkey = shfl64(key, l);
          bool c = (lane < MARGIN) && (bkey < stp_reg);
          uint64_t up = shfl_up64(stp_reg, 1);
          int cprev = __shfl_up((int)c, 1, 64);
          if (lane == 0) cprev = 0;
          if (c) stp_reg = cprev ? up : bkey;
        } while (m2);
        upd_tau();
      }
    }
  };

  // center row FIRST (bootstrap + tight tau), then remaining 8 box-1 rows
  scan_range(qcy, qcz, qcx - 1, qcx + 1);
#pragma unroll
  for (int dz = -1; dz <= 1; ++dz)
#pragma unroll
    for (int dy = -1; dy <= 1; ++dy)
      if (!(dy == 0 && dz == 0))
        scan_range(qcy + dy, qcz + dz, qcx - 1, qcx + 1);

  // shells r>=2 (rare)
  for (int r = 2; r < GRID; ++r) {
    float mrg = (float)(r - 1) * HCELL - deltaq;
    if (mrg > 0.0f && mrg * mrg > tau_f * 1.0001f) break;
    for (int dz = -r; dz <= r; ++dz)
      for (int dy = -r; dy <= r; ++dy) {
        if (abs(dz) == r || abs(dy) == r) {
          scan_range(qcy + dy, qcz + dz, qcx - r, qcx + r);
        } else {
          scan_range(qcy + dy, qcz + dz, qcx - r, qcx - r);
          scan_range(qcy + dy, qcz + dz, qcx + r, qcx + r);
        }
      }
  }

  if (lane < MARGIN) rid[wv][lane] = (int)(uint32_t)(stp_reg & 0xFFFFFFFFull);
  __syncthreads();

  // ---- exact f64 re-rank of 12 candidates (identical to R11-R15) ----
  const double xn = (double)xnf, yn = (double)ynf, zn = (double)znf;
  const double sqn = xn * xn + yn * yn + zn * zn;
  double myd2 = 0.0;
  int myid = 0;
  if (lane < MARGIN) {
    myid = rid[wv][lane];
    double gx = (double)sb[myid], gy = (double)sb[NPTS + myid], gz = (double)sb[2 * NPTS + myid];
    double gsq = gx * gx + gy * gy + gz * gz;
    double dot = xn * gx + yn * gy + zn * gz;
    double d2 = sqn + gsq - 2.0 * dot;
    if (d2 < 0.0) d2 = 0.0;
    myd2 = d2;
    rd2[wv][lane] = d2;
  }
  __syncthreads();
  if (lane < MARGIN) {
    int rk = 0;
    for (int m = 0; m < MARGIN; ++m) {
      double dm = rd2[wv][m];
      rk += (dm < myd2) || (dm == myd2 && rid[wv][m] < myid);
    }
    if (rk < KNN) snbr[wv][rk] = myid;
  }
  __syncthreads();

  // ---- phase 2 (identical to rounds 8-15) ----
  const double txn = (double)tb[n], tyn = (double)tb[NPTS + n], tzn = (double)tb[2 * NPTS + n];
  const int p = lane;
  double loss = 0.0, reg = 0.0;
  if (p < NPAIR) {
    int g1 = snbr[wv][dCOMB_A[p]];
    int g2 = snbr[wv][dCOMB_B[p]];

    double ax = (double)sb[g1] - xn, ay = (double)sb[NPTS + g1] - yn, az = (double)sb[2 * NPTS + g1] - zn;
    double bx = (double)sb[g2] - xn, by = (double)sb[NPTS + g2] - yn, bz = (double)sb[2 * NPTS + g2] - zn;
    double cx = ay * bz - az * by;
    double cy = az * bx - ax * bz;
    double cz = ax * by - ay * bx;
    double s  = cx * cx + cy * cy + cz * cz;
    double a_s = (s > 0.0) ? 0.5 * sqrt(s) : 0.0;

    double ux = (double)tb[g1] - txn, uy = (double)tb[NPTS + g1] - tyn, uz = (double)tb[2 * NPTS + g1] - tzn;
    double vx = (double)tb[g2] - txn, vy = (double)tb[NPTS + g2] - tyn, vz = (double)tb[2 * NPTS + g2] - tzn;
    double wx = uy * vz - uz * vy;
    double wy = uz * vx - ux * vz;
    double wz = ux * vy - uy * vx;
    double t2 = wx * wx + wy * wy + wz * wz;
    double a_t = (t2 > 0.0) ? 0.5 * sqrt(t2) : 0.0;

    double ate = a_t + EPSD;
    double d   = a_s - ate;
    double numer = (EPSD * EPSD + EPSD * EPSD) + d * d;
    double denom = (EPSD + EPSD) + (a_s + ate);
    loss = numer / denom;
    reg  = sqrt(numer);
    lsA[wv][p] = loss;
  }
  __syncthreads();

  if (p < NPAIR) {
    int rk = 0;
    for (int m = 0; m < NPAIR; ++m) {
      double lm = lsA[wv][m];
      rk += (lm < loss) || (lm == loss && m < p);
    }
    lsB[wv][rk] = loss;
  }
  __syncthreads();
  double tot2 = 0.0;
  if (p < NPAIR) {
    tot2 = lsB[wv][p] + 0.1 * reg;
    lsA[wv][p] = tot2;
  }
  __syncthreads();
  if (p < NPAIR) {
    int rk = 0;
    for (int m = 0; m < NPAIR; ++m) {
      double tm = lsA[wv][m];
      rk += (tm < tot2) || (tm == tot2 && m < p);
    }
    if (rk == (NPAIR - 1) / 2) smed[wv] = tot2;
  }
  __syncthreads();
  double med = smed[wv];
  if (p < KNN) {
    double t = (tot2 > 3.0 * med) ? 0.0 : tot2;
    ssum[wv][p] = sqrt(t + EPSD);
  }
  __syncthreads();
  if (lane == 0) {
    double sum = 0.0;
#pragma unroll
    for (int q = 0; q < KNN; ++q) sum += ssum[wv][q];
    mean_out[b * NPTS + n] = (float)(sum / 10.0);
  }
}

// ---------------- fallback: R11 full-scan kernels (unchanged) ----------------
__global__ __launch_bounds__(256) void pack_pts(const float* __restrict__ src,
                                                float4* __restrict__ pk) {
  int i = blockIdx.x * 256 + threadIdx.x;
  int b = i >> 13, p = i & (NPTS - 1);
  const float* sb = src + (size_t)b * 3 * NPTS;
  float x = sb[p], y = sb[NPTS + p], z = sb[2 * NPTS + p];
  pk[i] = make_float4(x, y, z, x * x + y * y + z * z);
}

template <bool PACKED>
__global__ __launch_bounds__(256) void gfm_wave(const float* __restrict__ src,
                                                const float* __restrict__ tgt,
                                                const float4* __restrict__ pk,
                                                float* __restrict__ mean_out) {
  __shared__ float4   s4[TILE];
  __shared__ uint64_t sqq[4][QSZ];
  __shared__ uint64_t stp[4][MARGIN];
  __shared__ double lsA[4][NPAIR];
  __shared__ double lsB[4][NPAIR];
  __shared__ double smed[4];
  __shared__ double ssum[4][KNN];
  __shared__ double rd2[4][MARGIN];
  __shared__ int    rid[4][MARGIN];
  __shared__ int    snbr[4][KNN];

  const int tid  = threadIdx.x;
  const int wv   = tid >> 6;
  const int lane = tid & 63;
  const int b    = blockIdx.x >> 11;
  const int n    = ((blockIdx.x & 2047) << 2) | wv;

  const float* __restrict__ sb = src + (size_t)b * 3 * NPTS;
  const float* __restrict__ tb = tgt + (size_t)b * 3 * NPTS;

  const float xnf = sb[n], ynf = sb[NPTS + n], znf = sb[2 * NPTS + n];
  const float sqnf = xnf * xnf + ynf * ynf + znf * znf;

  if (lane < MARGIN) stp[wv][lane] = ~0ull;
  __builtin_amdgcn_wave_barrier();
  float tau_f = __builtin_inff();
  int qn = 0;

  auto drain = [&]() {
    if (lane < MARGIN) sqq[wv][qn + lane] = stp[wv][lane];
    __builtin_amdgcn_wave_barrier();
    const int tot = qn + MARGIN;
    uint64_t k0 = (lane < tot) ? sqq[wv][lane] : ~0ull;
    uint64_t k1 = (lane + 64 < tot) ? sqq[wv][lane + 64] : ~0ull;
    int r0 = 0, r1 = 0;
    for (int m = 0; m < tot; ++m) {
      uint64_t km = sqq[wv][m];
      r0 += (km < k0);
      r1 += (km < k1);
    }
    __builtin_amdgcn_wave_barrier();
    if (lane < tot && r0 < MARGIN) stp[wv][r0] = k0;
    if (lane + 64 < tot && r1 < MARGIN) stp[wv][r1] = k1;
    __builtin_amdgcn_wave_barrier();
    tau_f = __uint_as_float((uint32_t)(stp[wv][MARGIN - 1] >> 32));
    qn = 0;
  };

  for (int t0 = 0; t0 < NPTS; t0 += TILE) {
    __syncthreads();
    if (PACKED) {
      const float4* __restrict__ g = pk + (size_t)b * NPTS + t0;
#pragma unroll
      for (int r = 0; r < TILE / 256; ++r) {
        int i = tid + r * 256;
        s4[i] = g[i];
      }
    } else {
#pragma unroll
      for (int r = 0; r < TILE / 256; ++r) {
        int i = tid + r * 256;
        float x = sb[t0 + i], y = sb[NPTS + t0 + i], z = sb[2 * NPTS + t0 + i];
        s4[i] = make_float4(x, y, z, x * x + y * y + z * z);
      }
    }
    __syncthreads();
#pragma unroll 2
    for (int r = 0; r < TILE / 64; ++r) {
      int j = lane + (r << 6);
      float4 c = s4[j];
      float dot = fmaf(xnf, c.x, fmaf(ynf, c.y, znf * c.z));
      float d2 = fmaxf(fmaf(-2.0f, dot, sqnf + c.w), 0.0f);
      bool pred = d2 <= tau_f;
      uint64_t mask = __ballot(pred);
      if (mask) {
        uint64_t key = ((uint64_t)__float_as_uint(d2) << 32) | (uint32_t)(t0 + j);
        int below = __builtin_amdgcn_mbcnt_hi((uint32_t)(mask >> 32),
                     __builtin_amdgcn_mbcnt_lo((uint32_t)mask, 0));
        if (pred) sqq[wv][qn + below] = key;
        __builtin_amdgcn_wave_barrier();
        qn += __popcll(mask);
        if (qn >= DRAIN_AT) drain();
      }
    }
  }
  if (qn > 0) drain();

  if (lane < MARGIN) rid[wv][lane] = (int)(uint32_t)(stp[wv][lane] & 0xFFFFFFFFull);
  __syncthreads();

  const double xn = (double)xnf, yn = (double)ynf, zn = (double)znf;
  const double sqn = xn * xn + yn * yn + zn * zn;
  double myd2 = 0.0;
  int myid = 0;
  if (lane < MARGIN) {
    myid = rid[wv][lane];
    double gx = (double)sb[myid], gy = (double)sb[NPTS + myid], gz = (double)sb[2 * NPTS + myid];
    double gsq = gx * gx + gy * gy + gz * gz;
    double dot = xn * gx + yn * gy + zn * gz;
    double d2 = sqn + gsq - 2.0 * dot;
    if (d2 < 0.0) d2 = 0.0;
    myd2 = d2;
    rd2[wv][lane] = d2;
  }
  __syncthreads();
  if (lane < MARGIN) {
    int rk = 0;
    for (int m = 0; m < MARGIN; ++m) {
      double dm = rd2[wv][m];
      rk += (dm < myd2) || (dm == myd2 && rid[wv][m] < myid);
    }
    if (rk < KNN) snbr[wv][rk] = myid;
  }
  __syncthreads();

  const double txn = (double)tb[n], tyn = (double)tb[NPTS + n], tzn = (double)tb[2 * NPTS + n];
  const int p = lane;
  double loss = 0.0, reg = 0.0;
  if (p < NPAIR) {
    int g1 = snbr[wv][dCOMB_A[p]];
    int g2 = snbr[wv][dCOMB_B[p]];

    double ax = (double)sb[g1] - xn, ay = (double)sb[NPTS + g1] - yn, az = (double)sb[2 * NPTS + g1] - zn;
    double bx = (double)sb[g2] - xn, by = (double)sb[NPTS + g2] - yn, bz = (double)sb[2 * NPTS + g2] - zn;
    double cx = ay * bz - az * by;
    double cy = az * bx - ax * bz;
    double cz = ax * by - ay * bx;
    double s  = cx * cx + cy * cy + cz * cz;
    double a_s = (s > 0.0) ? 0.5 * sqrt(s) : 0.0;

    double ux = (double)tb[g1] - txn, uy = (double)tb[NPTS + g1] - tyn, uz = (double)tb[2 * NPTS + g1] - tzn;
    double vx = (double)tb[g2] - txn, vy = (double)tb[NPTS + g2] - tyn, vz = (double)tb[2 * NPTS + g2] - tzn;
    double wx = uy * vz - uz * vy;
    double wy = uz * vx - ux * vz;
    double wz = ux * vy - uy * vx;
    double t2 = wx * wx + wy * wy + wz * wz;
    double a_t = (t2 > 0.0) ? 0.5 * sqrt(t2) : 0.0;

    double ate = a_t + EPSD;
    double d   = a_s - ate;
    double numer = (EPSD * EPSD + EPSD * EPSD) + d * d;
    double denom = (EPSD + EPSD) + (a_s + ate);
    loss = numer / denom;
    reg  = sqrt(numer);
    lsA[wv][p] = loss;
  }
  __syncthreads();

  if (p < NPAIR) {
    int rk = 0;
    for (int m = 0; m < NPAIR; ++m) {
      double lm = lsA[wv][m];
      rk += (lm < loss) || (lm == loss && m < p);
    }
    lsB[wv][rk] = loss;
  }
  __syncthreads();
  double tot2 = 0.0;
  if (p < NPAIR) {
    tot2 = lsB[wv][p] + 0.1 * reg;
    lsA[wv][p] = tot2;
  }
  __syncthreads();
  if (p < NPAIR) {
    int rk = 0;
    for (int m = 0; m < NPAIR; ++m) {
      double tm = lsA[wv][m];
      rk += (tm < tot2) || (tm == tot2 && m < p);
    }
    if (rk == (NPAIR - 1) / 2) smed[wv] = tot2;
  }
  __syncthreads();
  double med = smed[wv];
  if (p < KNN) {
    double t = (tot2 > 3.0 * med) ? 0.0 : tot2;
    ssum[wv][p] = sqrt(t + EPSD);
  }
  __syncthreads();
  if (lane == 0) {
    double sum = 0.0;
#pragma unroll
    for (int q = 0; q < KNN; ++q) sum += ssum[wv][q];
    mean_out[b * NPTS + n] = (float)(sum / 10.0);
  }
}

// ---------------- finalize (unchanged) ----------------
__global__ __launch_bounds__(1024) void gfm_finalize(float* __restrict__ buf) {
  __shared__ float red[16];
  const int b = blockIdx.x;
  const int tid = threadIdx.x;
  float* __restrict__ mb = buf + b * NPTS;

  float v[8];
  float mn = 3.4e38f;
#pragma unroll
  for (int r = 0; r < 8; ++r) {
    v[r] = mb[tid + r * 1024];
    mn = fminf(mn, v[r]);
  }
#pragma unroll
  for (int s = 32; s >= 1; s >>= 1)
    mn = fminf(mn, __shfl_xor(mn, s, 64));
  if ((tid & 63) == 0) red[tid >> 6] = mn;
  __syncthreads();
  mn = red[0];
#pragma unroll
  for (int q = 1; q < 16; ++q) mn = fminf(mn, red[q]);
  __syncthreads();

#pragma unroll
  for (int r = 0; r < 8; ++r) {
    double t = (double)v[r] - (double)mn;
    double w = 2.0 / (1.0 + exp(20.0 * t));
    mb[tid + r * 1024] = (w > 0.5) ? 1.0f : 0.0f;
  }
}

extern "C" void kernel_launch(void* const* d_in, const int* in_sizes, int n_in,
                              void* d_out, int out_size, void* d_ws, size_t ws_size,
                              hipStream_t stream) {
  const float* src = (const float*)d_in[0];
  const float* tgt = (const float*)d_in[1];
  float* out = (float*)d_out;

  const size_t nP = (size_t)NBATCH * NPTS;
  const size_t sz_pts  = nP * sizeof(float4);
  const size_t sz_oidx = nP * sizeof(uint32_t);
  const size_t sz_cs   = (size_t)NBATCH * (NCELL + 1) * 4;
  const size_t need = sz_pts + sz_oidx + sz_cs;

  if (ws_size >= need) {
    char* w = (char*)d_ws;
    float4*   pts = (float4*)w;
    uint32_t* oid = (uint32_t*)(w + sz_pts);
    uint32_t* cst = (uint32_t*)(w + sz_pts + sz_oidx);

    grid_build<<<NBATCH, 1024, 0, stream>>>(src, pts, oid, cst);
    gfm_grid<<<NBATCH * NPTS / 4, 256, 0, stream>>>(src, tgt, pts, oid, cst, out);
  } else if (ws_size >= sz_pts) {
    float4* pk = (float4*)d_ws;
    pack_pts<<<(int)(nP / 256), 256, 0, stream>>>(src, pk);
    gfm_wave<true><<<NBATCH * NPTS / 4, 256, 0, stream>>>(src, tgt, pk, out);
  } else {
    gfm_wave<false><<<NBATCH * NPTS / 4, 256, 0, stream>>>(src, tgt, nullptr, out);
  }
  gfm_finalize<<<NBATCH, 1024, 0, stream>>>(out);
}

// Round 17
// 143.428 us; speedup vs baseline: 1.2714x; 1.2714x over previous
//
#include <hip/hip_runtime.h>
#include <cstdint>
#include <cstddef>

#define NPTS 8192
#define NBATCH 4
#define KNN 10
#define NPAIR 45
#define TILE 512
#define MARGIN 12
#define QSZ 128
#define DRAIN_AT 52
#define EPSD 1e-6
#define GRID 14
#define NCELL (GRID*GRID*GRID)
#define HCELL 0.7f
#define ORG (-4.9f)

__device__ __constant__ int dCOMB_A[NPAIR] = {
  0,0,0,0,0,0,0,0,0, 1,1,1,1,1,1,1,1, 2,2,2,2,2,2,2,
  3,3,3,3,3,3, 4,4,4,4,4, 5,5,5,5, 6,6,6, 7,7, 8};
__device__ __constant__ int dCOMB_B[NPAIR] = {
  1,2,3,4,5,6,7,8,9, 2,3,4,5,6,7,8,9, 3,4,5,6,7,8,9,
  4,5,6,7,8,9, 5,6,7,8,9, 6,7,8,9, 7,8,9, 8,9, 9};

__device__ __forceinline__ void cell_coords(float x, float y, float z,
                                            int& cx, int& cy, int& cz) {
  cx = (int)floorf((x - ORG) * (1.0f / HCELL));
  cy = (int)floorf((y - ORG) * (1.0f / HCELL));
  cz = (int)floorf((z - ORG) * (1.0f / HCELL));
  cx = min(max(cx, 0), GRID - 1);
  cy = min(max(cy, 0), GRID - 1);
  cz = min(max(cz, 0), GRID - 1);
}

// ---------------- fused grid build: one block per batch (R15, proven) ----------------
__global__ __launch_bounds__(1024) void grid_build(const float* __restrict__ src,
                                                   float4* __restrict__ pts,
                                                   uint32_t* __restrict__ oidx,
                                                   uint32_t* __restrict__ cstart) {
  __shared__ uint32_t scnt[NCELL];
  __shared__ uint32_t swv[16];
  const int b = blockIdx.x;
  const int tid = threadIdx.x, lane = tid & 63, wid = tid >> 6;
  const float* __restrict__ sb = src + (size_t)b * 3 * NPTS;

  for (int i = tid; i < NCELL; i += 1024) scnt[i] = 0;
  __syncthreads();

  float px[8], py[8], pz[8];
  int pc[8];
#pragma unroll
  for (int k = 0; k < 8; ++k) {
    int p = tid + k * 1024;
    float x = sb[p], y = sb[NPTS + p], z = sb[2 * NPTS + p];
    px[k] = x; py[k] = y; pz[k] = z;
    int cx, cy, cz;
    cell_coords(x, y, z, cx, cy, cz);
    pc[k] = ((cz * GRID) + cy) * GRID + cx;
    atomicAdd(&scnt[pc[k]], 1u);
  }
  __syncthreads();

  const int i0 = tid * 4;
  uint32_t v[4], ts = 0;
#pragma unroll
  for (int k = 0; k < 4; ++k) {
    v[k] = (i0 + k < NCELL) ? scnt[i0 + k] : 0u;
    ts += v[k];
  }
  uint32_t x = ts;
#pragma unroll
  for (int off = 1; off < 64; off <<= 1) {
    uint32_t y = __shfl_up(x, off, 64);
    if (lane >= off) x += y;
  }
  if (lane == 63) swv[wid] = x;
  __syncthreads();
  uint32_t wpre = 0, bsum = 0;
  for (int w = 0; w < 16; ++w) { uint32_t s = swv[w]; bsum += s; if (w < wid) wpre += s; }
  uint32_t excl = wpre + (x - ts);
#pragma unroll
  for (int k = 0; k < 4; ++k) {
    if (i0 + k < NCELL) {
      cstart[b * (NCELL + 1) + i0 + k] = excl;
      scnt[i0 + k] = excl;
      excl += v[k];
    }
  }
  if (tid == 0) cstart[b * (NCELL + 1) + NCELL] = bsum;
  __syncthreads();

#pragma unroll
  for (int k = 0; k < 8; ++k) {
    uint32_t pos = atomicAdd(&scnt[pc[k]], 1u);
    pts[(b << 13) + pos]  = make_float4(px[k], py[k], pz[k],
                                        px[k] * px[k] + py[k] * py[k] + pz[k] * pz[k]);
    oidx[(b << 13) + pos] = (uint32_t)(tid + k * 1024);
  }
}

// ---------------- main: R14 body + single-slot drain ----------------
__global__ __launch_bounds__(256) void gfm_grid(const float* __restrict__ src,
                                                const float* __restrict__ tgt,
                                                const float4* __restrict__ pts,
                                                const uint32_t* __restrict__ oidx,
                                                const uint32_t* __restrict__ cstart,
                                                float* __restrict__ mean_out) {
  __shared__ uint64_t sqq[4][QSZ];
  __shared__ uint64_t stp[4][MARGIN];
  __shared__ double lsA[4][NPAIR];
  __shared__ double lsB[4][NPAIR];
  __shared__ double smed[4];
  __shared__ double ssum[4][KNN];
  __shared__ double rd2[4][MARGIN];
  __shared__ int    rid[4][MARGIN];
  __shared__ int    snbr[4][KNN];

  const int tid  = threadIdx.x;
  const int wv   = tid >> 6;
  const int lane = tid & 63;
  const int b    = blockIdx.x >> 11;
  const int n    = ((blockIdx.x & 2047) << 2) | wv;

  const float* __restrict__ sb = src + (size_t)b * 3 * NPTS;
  const float* __restrict__ tb = tgt + (size_t)b * 3 * NPTS;
  const float4* __restrict__ ppts = pts + ((size_t)b << 13);
  const uint32_t* __restrict__ poid = oidx + ((size_t)b << 13);
  const uint32_t* __restrict__ cs = cstart + (size_t)b * (NCELL + 1);

  const float xnf = sb[n], ynf = sb[NPTS + n], znf = sb[2 * NPTS + n];
  const float sqnf = xnf * xnf + ynf * ynf + znf * znf;

  int qcx, qcy, qcz;
  cell_coords(xnf, ynf, znf, qcx, qcy, qcz);
  float lox = ORG + qcx * HCELL, loy = ORG + qcy * HCELL, loz = ORG + qcz * HCELL;
  float dqx = fmaxf(fmaxf(lox - xnf, xnf - (lox + HCELL)), 0.0f);
  float dqy = fmaxf(fmaxf(loy - ynf, ynf - (loy + HCELL)), 0.0f);
  float dqz = fmaxf(fmaxf(loz - znf, znf - (loz + HCELL)), 0.0f);
  const float deltaq = sqrtf(dqx * dqx + dqy * dqy + dqz * dqz);

  if (lane < MARGIN) stp[wv][lane] = ~0ull;
  __builtin_amdgcn_wave_barrier();
  float tau_f = __builtin_inff();
  int qn = 0;          // wave-uniform
  bool boot = false;   // wave-uniform: becomes true after first drain

  auto drain = [&]() {
    int tot = qn;
    if (boot) {
      if (lane < MARGIN) sqq[wv][qn + lane] = stp[wv][lane];
      tot = qn + MARGIN;
    }
    __builtin_amdgcn_wave_barrier();
    if (tot <= 64) {
      // single-slot rank: 1 cmp per iteration
      uint64_t k0 = (lane < tot) ? sqq[wv][lane] : ~0ull;
      int r0 = 0;
      for (int m = 0; m < tot; ++m) r0 += (sqq[wv][m] < k0);
      __builtin_amdgcn_wave_barrier();
      if (lane < tot && r0 < MARGIN) stp[wv][r0] = k0;
    } else {
      uint64_t k0 = (lane < tot) ? sqq[wv][lane] : ~0ull;
      uint64_t k1 = (lane + 64 < tot) ? sqq[wv][lane + 64] : ~0ull;
      int r0 = 0, r1 = 0;
      for (int m = 0; m < tot; ++m) {
        uint64_t km = sqq[wv][m];
        r0 += (km < k0);
        r1 += (km < k1);
      }
      __builtin_amdgcn_wave_barrier();
      if (lane < tot && r0 < MARGIN) stp[wv][r0] = k0;
      if (lane + 64 < tot && r1 < MARGIN) stp[wv][r1] = k1;
    }
    __builtin_amdgcn_wave_barrier();
    tau_f = __uint_as_float((uint32_t)(stp[wv][MARGIN - 1] >> 32));
    boot = true;
    qn = 0;
  };

  auto scan_range = [&](int cy, int cz, int cx0, int cx1) {
    if (cy < 0 || cy >= GRID || cz < 0 || cz >= GRID) return;
    cx0 = max(cx0, 0); cx1 = min(cx1, GRID - 1);
    if (cx0 > cx1) return;
    float bx0 = ORG + cx0 * HCELL, bx1 = ORG + (cx1 + 1) * HCELL;
    float by0 = ORG + cy * HCELL,  by1 = by0 + HCELL;
    float bz0 = ORG + cz * HCELL,  bz1 = bz0 + HCELL;
    float ddx = fmaxf(fmaxf(bx0 - xnf, xnf - bx1), 0.0f);
    float ddy = fmaxf(fmaxf(by0 - ynf, ynf - by1), 0.0f);
    float ddz = fmaxf(fmaxf(bz0 - znf, znf - bz1), 0.0f);
    float rowmin = ddx * ddx + ddy * ddy + ddz * ddz;
    if (rowmin > tau_f * 1.001f + 1e-5f) return;   // inf-safe, conservative
    uint32_t c0 = (uint32_t)(((cz * GRID) + cy) * GRID + cx0);
    uint32_t st = cs[c0];
    uint32_t en = cs[c0 + (uint32_t)(cx1 - cx0) + 1];
    for (uint32_t base = st; base < en; base += 64) {
      uint32_t pp = base + (uint32_t)lane;
      bool act = pp < en;
      float d2 = 0.0f;
      bool pred = false;
      if (act) {
        float4 c4 = ppts[pp];
        float dot = fmaf(xnf, c4.x, fmaf(ynf, c4.y, znf * c4.z));
        d2 = fmaxf(fmaf(-2.0f, dot, sqnf + c4.w), 0.0f);
        pred = d2 <= tau_f;
      }
      uint64_t m2 = __ballot(pred);
      if (m2) {
        int below = __builtin_amdgcn_mbcnt_hi((uint32_t)(m2 >> 32),
                     __builtin_amdgcn_mbcnt_lo((uint32_t)m2, 0));
        if (pred) {
          uint64_t key = ((uint64_t)__float_as_uint(d2) << 32) | (uint64_t)poid[pp];
          sqq[wv][qn + below] = key;
        }
        __builtin_amdgcn_wave_barrier();
        qn += __popcll(m2);
        if (qn >= DRAIN_AT) drain();
      }
    }
  };

  // center row FIRST (tightens tau immediately), then remaining 8 box-1 rows
  scan_range(qcy, qcz, qcx - 1, qcx + 1);
#pragma unroll
  for (int dz = -1; dz <= 1; ++dz)
#pragma unroll
    for (int dy = -1; dy <= 1; ++dy)
      if (!(dy == 0 && dz == 0))
        scan_range(qcy + dy, qcz + dz, qcx - 1, qcx + 1);

  // shells r>=2 (rare)
  for (int r = 2; r < GRID; ++r) {
    float mrg = (float)(r - 1) * HCELL - deltaq;
    if (mrg > 0.0f && mrg * mrg > tau_f * 1.0001f) break;
    for (int dz = -r; dz <= r; ++dz)
      for (int dy = -r; dy <= r; ++dy) {
        if (abs(dz) == r || abs(dy) == r) {
          scan_range(qcy + dy, qcz + dz, qcx - r, qcx + r);
        } else {
          scan_range(qcy + dy, qcz + dz, qcx - r, qcx - r);
          scan_range(qcy + dy, qcz + dz, qcx + r, qcx + r);
        }
      }
  }
  if (qn > 0) drain();

  if (lane < MARGIN) rid[wv][lane] = (int)(uint32_t)(stp[wv][lane] & 0xFFFFFFFFull);
  __syncthreads();

  // ---- exact f64 re-rank of 12 candidates (identical to R11-R15) ----
  const double xn = (double)xnf, yn = (double)ynf, zn = (double)znf;
  const double sqn = xn * xn + yn * yn + zn * zn;
  double myd2 = 0.0;
  int myid = 0;
  if (lane < MARGIN) {
    myid = rid[wv][lane];
    double gx = (double)sb[myid], gy = (double)sb[NPTS + myid], gz = (double)sb[2 * NPTS + myid];
    double gsq = gx * gx + gy * gy + gz * gz;
    double dot = xn * gx + yn * gy + zn * gz;
    double d2 = sqn + gsq - 2.0 * dot;
    if (d2 < 0.0) d2 = 0.0;
    myd2 = d2;
    rd2[wv][lane] = d2;
  }
  __syncthreads();
  if (lane < MARGIN) {
    int rk = 0;
    for (int m = 0; m < MARGIN; ++m) {
      double dm = rd2[wv][m];
      rk += (dm < myd2) || (dm == myd2 && rid[wv][m] < myid);
    }
    if (rk < KNN) snbr[wv][rk] = myid;
  }
  __syncthreads();

  // ---- phase 2 (identical to rounds 8-15) ----
  const double txn = (double)tb[n], tyn = (double)tb[NPTS + n], tzn = (double)tb[2 * NPTS + n];
  const int p = lane;
  double loss = 0.0, reg = 0.0;
  if (p < NPAIR) {
    int g1 = snbr[wv][dCOMB_A[p]];
    int g2 = snbr[wv][dCOMB_B[p]];

    double ax = (double)sb[g1] - xn, ay = (double)sb[NPTS + g1] - yn, az = (double)sb[2 * NPTS + g1] - zn;
    double bx = (double)sb[g2] - xn, by = (double)sb[NPTS + g2] - yn, bz = (double)sb[2 * NPTS + g2] - zn;
    double cx = ay * bz - az * by;
    double cy = az * bx - ax * bz;
    double cz = ax * by - ay * bx;
    double s  = cx * cx + cy * cy + cz * cz;
    double a_s = (s > 0.0) ? 0.5 * sqrt(s) : 0.0;

    double ux = (double)tb[g1] - txn, uy = (double)tb[NPTS + g1] - tyn, uz = (double)tb[2 * NPTS + g1] - tzn;
    double vx = (double)tb[g2] - txn, vy = (double)tb[NPTS + g2] - tyn, vz = (double)tb[2 * NPTS + g2] - tzn;
    double wx = uy * vz - uz * vy;
    double wy = uz * vx - ux * vz;
    double wz = ux * vy - uy * vx;
    double t2 = wx * wx + wy * wy + wz * wz;
    double a_t = (t2 > 0.0) ? 0.5 * sqrt(t2) : 0.0;

    double ate = a_t + EPSD;
    double d   = a_s - ate;
    double numer = (EPSD * EPSD + EPSD * EPSD) + d * d;
    double denom = (EPSD + EPSD) + (a_s + ate);
    loss = numer / denom;
    reg  = sqrt(numer);
    lsA[wv][p] = loss;
  }
  __syncthreads();

  if (p < NPAIR) {
    int rk = 0;
    for (int m = 0; m < NPAIR; ++m) {
      double lm = lsA[wv][m];
      rk += (lm < loss) || (lm == loss && m < p);
    }
    lsB[wv][rk] = loss;
  }
  __syncthreads();
  double tot2 = 0.0;
  if (p < NPAIR) {
    tot2 = lsB[wv][p] + 0.1 * reg;
    lsA[wv][p] = tot2;
  }
  __syncthreads();
  if (p < NPAIR) {
    int rk = 0;
    for (int m = 0; m < NPAIR; ++m) {
      double tm = lsA[wv][m];
      rk += (tm < tot2) || (tm == tot2 && m < p);
    }
    if (rk == (NPAIR - 1) / 2) smed[wv] = tot2;
  }
  __syncthreads();
  double med = smed[wv];
  if (p < KNN) {
    double t = (tot2 > 3.0 * med) ? 0.0 : tot2;
    ssum[wv][p] = sqrt(t + EPSD);
  }
  __syncthreads();
  if (lane == 0) {
    double sum = 0.0;
#pragma unroll
    for (int q = 0; q < KNN; ++q) sum += ssum[wv][q];
    mean_out[b * NPTS + n] = (float)(sum / 10.0);
  }
}

// ---------------- fallback: R11 full-scan kernels (unchanged) ----------------
__global__ __launch_bounds__(256) void pack_pts(const float* __restrict__ src,
                                                float4* __restrict__ pk) {
  int i = blockIdx.x * 256 + threadIdx.x;
  int b = i >> 13, p = i & (NPTS - 1);
  const float* sb = src + (size_t)b * 3 * NPTS;
  float x = sb[p], y = sb[NPTS + p], z = sb[2 * NPTS + p];
  pk[i] = make_float4(x, y, z, x * x + y * y + z * z);
}

template <bool PACKED>
__global__ __launch_bounds__(256) void gfm_wave(const float* __restrict__ src,
                                                const float* __restrict__ tgt,
                                                const float4* __restrict__ pk,
                                                float* __restrict__ mean_out) {
  __shared__ float4   s4[TILE];
  __shared__ uint64_t sqq[4][QSZ];
  __shared__ uint64_t stp[4][MARGIN];
  __shared__ double lsA[4][NPAIR];
  __shared__ double lsB[4][NPAIR];
  __shared__ double smed[4];
  __shared__ double ssum[4][KNN];
  __shared__ double rd2[4][MARGIN];
  __shared__ int    rid[4][MARGIN];
  __shared__ int    snbr[4][KNN];

  const int tid  = threadIdx.x;
  const int wv   = tid >> 6;
  const int lane = tid & 63;
  const int b    = blockIdx.x >> 11;
  const int n    = ((blockIdx.x & 2047) << 2) | wv;

  const float* __restrict__ sb = src + (size_t)b * 3 * NPTS;
  const float* __restrict__ tb = tgt + (size_t)b * 3 * NPTS;

  const float xnf = sb[n], ynf = sb[NPTS + n], znf = sb[2 * NPTS + n];
  const float sqnf = xnf * xnf + ynf * ynf + znf * znf;

  if (lane < MARGIN) stp[wv][lane] = ~0ull;
  __builtin_amdgcn_wave_barrier();
  float tau_f = __builtin_inff();
  int qn = 0;
  bool boot = false;

  auto drain = [&]() {
    int tot = qn;
    if (boot) {
      if (lane < MARGIN) sqq[wv][qn + lane] = stp[wv][lane];
      tot = qn + MARGIN;
    }
    __builtin_amdgcn_wave_barrier();
    if (tot <= 64) {
      uint64_t k0 = (lane < tot) ? sqq[wv][lane] : ~0ull;
      int r0 = 0;
      for (int m = 0; m < tot; ++m) r0 += (sqq[wv][m] < k0);
      __builtin_amdgcn_wave_barrier();
      if (lane < tot && r0 < MARGIN) stp[wv][r0] = k0;
    } else {
      uint64_t k0 = (lane < tot) ? sqq[wv][lane] : ~0ull;
      uint64_t k1 = (lane + 64 < tot) ? sqq[wv][lane + 64] : ~0ull;
      int r0 = 0, r1 = 0;
      for (int m = 0; m < tot; ++m) {
        uint64_t km = sqq[wv][m];
        r0 += (km < k0);
        r1 += (km < k1);
      }
      __builtin_amdgcn_wave_barrier();
      if (lane < tot && r0 < MARGIN) stp[wv][r0] = k0;
      if (lane + 64 < tot && r1 < MARGIN) stp[wv][r1] = k1;
    }
    __builtin_amdgcn_wave_barrier();
    tau_f = __uint_as_float((uint32_t)(stp[wv][MARGIN - 1] >> 32));
    boot = true;
    qn = 0;
  };

  for (int t0 = 0; t0 < NPTS; t0 += TILE) {
    __syncthreads();
    if (PACKED) {
      const float4* __restrict__ g = pk + (size_t)b * NPTS + t0;
#pragma unroll
      for (int r = 0; r < TILE / 256; ++r) {
        int i = tid + r * 256;
        s4[i] = g[i];
      }
    } else {
#pragma unroll
      for (int r = 0; r < TILE / 256; ++r) {
        int i = tid + r * 256;
        float x = sb[t0 + i], y = sb[NPTS + t0 + i], z = sb[2 * NPTS + t0 + i];
        s4[i] = make_float4(x, y, z, x * x + y * y + z * z);
      }
    }
    __syncthreads();
#pragma unroll 2
    for (int r = 0; r < TILE / 64; ++r) {
      int j = lane + (r << 6);
      float4 c = s4[j];
      float dot = fmaf(xnf, c.x, fmaf(ynf, c.y, znf * c.z));
      float d2 = fmaxf(fmaf(-2.0f, dot, sqnf + c.w), 0.0f);
      bool pred = d2 <= tau_f;
      uint64_t mask = __ballot(pred);
      if (mask) {
        uint64_t key = ((uint64_t)__float_as_uint(d2) << 32) | (uint32_t)(t0 + j);
        int below = __builtin_amdgcn_mbcnt_hi((uint32_t)(mask >> 32),
                     __builtin_amdgcn_mbcnt_lo((uint32_t)mask, 0));
        if (pred) sqq[wv][qn + below] = key;
        __builtin_amdgcn_wave_barrier();
        qn += __popcll(mask);
        if (qn >= DRAIN_AT) drain();
      }
    }
  }
  if (qn > 0) drain();

  if (lane < MARGIN) rid[wv][lane] = (int)(uint32_t)(stp[wv][lane] & 0xFFFFFFFFull);
  __syncthreads();

  const double xn = (double)xnf, yn = (double)ynf, zn = (double)znf;
  const double sqn = xn * xn + yn * yn + zn * zn;
  double myd2 = 0.0;
  int myid = 0;
  if (lane < MARGIN) {
    myid = rid[wv][lane];
    double gx = (double)sb[myid], gy = (double)sb[NPTS + myid], gz = (double)sb[2 * NPTS + myid];
    double gsq = gx * gx + gy * gy + gz * gz;
    double dot = xn * gx + yn * gy + zn * gz;
    double d2 = sqn + gsq - 2.0 * dot;
    if (d2 < 0.0) d2 = 0.0;
    myd2 = d2;
    rd2[wv][lane] = d2;
  }
  __syncthreads();
  if (lane < MARGIN) {
    int rk = 0;
    for (int m = 0; m < MARGIN; ++m) {
      double dm = rd2[wv][m];
      rk += (dm < myd2) || (dm == myd2 && rid[wv][m] < myid);
    }
    if (rk < KNN) snbr[wv][rk] = myid;
  }
  __syncthreads();

  const double txn = (double)tb[n], tyn = (double)tb[NPTS + n], tzn = (double)tb[2 * NPTS + n];
  const int p = lane;
  double loss = 0.0, reg = 0.0;
  if (p < NPAIR) {
    int g1 = snbr[wv][dCOMB_A[p]];
    int g2 = snbr[wv][dCOMB_B[p]];

    double ax = (double)sb[g1] - xn, ay = (double)sb[NPTS + g1] - yn, az = (double)sb[2 * NPTS + g1] - zn;
    double bx = (double)sb[g2] - xn, by = (double)sb[NPTS + g2] - yn, bz = (double)sb[2 * NPTS + g2] - zn;
    double cx = ay * bz - az * by;
    double cy = az * bx - ax * bz;
    double cz = ax * by - ay * bx;
    double s  = cx * cx + cy * cy + cz * cz;
    double a_s = (s > 0.0) ? 0.5 * sqrt(s) : 0.0;

    double ux = (double)tb[g1] - txn, uy = (double)tb[NPTS + g1] - tyn, uz = (double)tb[2 * NPTS + g1] - tzn;
    double vx = (double)tb[g2] - txn, vy = (double)tb[NPTS + g2] - tyn, vz = (double)tb[2 * NPTS + g2] - tzn;
    double wx = uy * vz - uz * vy;
    double wy = uz * vx - ux * vz;
    double wz = ux * vy - uy * vx;
    double t2 = wx * wx + wy * wy + wz * wz;
    double a_t = (t2 > 0.0) ? 0.5 * sqrt(t2) : 0.0;

    double ate = a_t + EPSD;
    double d   = a_s - ate;
    double numer = (EPSD * EPSD + EPSD * EPSD) + d * d;
    double denom = (EPSD + EPSD) + (a_s + ate);
    loss = numer / denom;
    reg  = sqrt(numer);
    lsA[wv][p] = loss;
  }
  __syncthreads();

  if (p < NPAIR) {
    int rk = 0;
    for (int m = 0; m < NPAIR; ++m) {
      double lm = lsA[wv][m];
      rk += (lm < loss) || (lm == loss && m < p);
    }
    lsB[wv][rk] = loss;
  }
  __syncthreads();
  double tot2 = 0.0;
  if (p < NPAIR) {
    tot2 = lsB[wv][p] + 0.1 * reg;
    lsA[wv][p] = tot2;
  }
  __syncthreads();
  if (p < NPAIR) {
    int rk = 0;
    for (int m = 0; m < NPAIR; ++m) {
      double tm = lsA[wv][m];
      rk += (tm < tot2) || (tm == tot2 && m < p);
    }
    if (rk == (NPAIR - 1) / 2) smed[wv] = tot2;
  }
  __syncthreads();
  double med = smed[wv];
  if (p < KNN) {
    double t = (tot2 > 3.0 * med) ? 0.0 : tot2;
    ssum[wv][p] = sqrt(t + EPSD);
  }
  __syncthreads();
  if (lane == 0) {
    double sum = 0.0;
#pragma unroll
    for (int q = 0; q < KNN; ++q) sum += ssum[wv][q];
    mean_out[b * NPTS + n] = (float)(sum / 10.0);
  }
}

// ---------------- finalize (unchanged) ----------------
__global__ __launch_bounds__(1024) void gfm_finalize(float* __restrict__ buf) {
  __shared__ float red[16];
  const int b = blockIdx.x;
  const int tid = threadIdx.x;
  float* __restrict__ mb = buf + b * NPTS;

  float v[8];
  float mn = 3.4e38f;
#pragma unroll
  for (int r = 0; r < 8; ++r) {
    v[r] = mb[tid + r * 1024];
    mn = fminf(mn, v[r]);
  }
#pragma unroll
  for (int s = 32; s >= 1; s >>= 1)
    mn = fminf(mn, __shfl_xor(mn, s, 64));
  if ((tid & 63) == 0) red[tid >> 6] = mn;
  __syncthreads();
  mn = red[0];
#pragma unroll
  for (int q = 1; q < 16; ++q) mn = fminf(mn, red[q]);
  __syncthreads();

#pragma unroll
  for (int r = 0; r < 8; ++r) {
    double t = (double)v[r] - (double)mn;
    double w = 2.0 / (1.0 + exp(20.0 * t));
    mb[tid + r * 1024] = (w > 0.5) ? 1.0f : 0.0f;
  }
}

extern "C" void kernel_launch(void* const* d_in, const int* in_sizes, int n_in,
                              void* d_out, int out_size, void* d_ws, size_t ws_size,
                              hipStream_t stream) {
  const float* src = (const float*)d_in[0];
  const float* tgt = (const float*)d_in[1];
  float* out = (float*)d_out;

  const size_t nP = (size_t)NBATCH * NPTS;
  const size_t sz_pts  = nP * sizeof(float4);
  const size_t sz_oidx = nP * sizeof(uint32_t);
  const size_t sz_cs   = (size_t)NBATCH * (NCELL + 1) * 4;
  const size_t need = sz_pts + sz_oidx + sz_cs;

  if (ws_size >= need) {
    char* w = (char*)d_ws;
    float4*   pts = (float4*)w;
    uint32_t* oid = (uint32_t*)(w + sz_pts);
    uint32_t* cst = (uint32_t*)(w + sz_pts + sz_oidx);

    grid_build<<<NBATCH, 1024, 0, stream>>>(src, pts, oid, cst);
    gfm_grid<<<NBATCH * NPTS / 4, 256, 0, stream>>>(src, tgt, pts, oid, cst, out);
  } else if (ws_size >= sz_pts) {
    float4* pk = (float4*)d_ws;
    pack_pts<<<(int)(nP / 256), 256, 0, stream>>>(src, pk);
    gfm_wave<true><<<NBATCH * NPTS / 4, 256, 0, stream>>>(src, tgt, pk, out);
  } else {
    gfm_wave<false><<<NBATCH * NPTS / 4, 256, 0, stream>>>(src, tgt, nullptr, out);
  }
  gfm_finalize<<<NBATCH, 1024, 0, stream>>>(out);
}

// Round 18
// 136.457 us; speedup vs baseline: 1.3363x; 1.0511x over previous
//
#include <hip/hip_runtime.h>
#include <cstdint>
#include <cstddef>

#define NPTS 8192
#define NBATCH 4
#define KNN 10
#define NPAIR 45
#define TILE 512
#define MARGIN 12
#define QSZ 128
#define DRAIN_AT 52
#define EPSD 1e-6
#define GRID 14
#define NCELL (GRID*GRID*GRID)
#define HCELL 0.7f
#define ORG (-4.9f)

#define WVBAR() __builtin_amdgcn_wave_barrier()

__device__ __constant__ int dCOMB_A[NPAIR] = {
  0,0,0,0,0,0,0,0,0, 1,1,1,1,1,1,1,1, 2,2,2,2,2,2,2,
  3,3,3,3,3,3, 4,4,4,4,4, 5,5,5,5, 6,6,6, 7,7, 8};
__device__ __constant__ int dCOMB_B[NPAIR] = {
  1,2,3,4,5,6,7,8,9, 2,3,4,5,6,7,8,9, 3,4,5,6,7,8,9,
  4,5,6,7,8,9, 5,6,7,8,9, 6,7,8,9, 7,8,9, 8,9, 9};

__device__ __forceinline__ void cell_coords(float x, float y, float z,
                                            int& cx, int& cy, int& cz) {
  cx = (int)floorf((x - ORG) * (1.0f / HCELL));
  cy = (int)floorf((y - ORG) * (1.0f / HCELL));
  cz = (int)floorf((z - ORG) * (1.0f / HCELL));
  cx = min(max(cx, 0), GRID - 1);
  cy = min(max(cy, 0), GRID - 1);
  cz = min(max(cz, 0), GRID - 1);
}

// ---------------- fused grid build: one block per batch (R15, proven) ----------------
__global__ __launch_bounds__(1024) void grid_build(const float* __restrict__ src,
                                                   float4* __restrict__ pts,
                                                   uint32_t* __restrict__ oidx,
                                                   uint32_t* __restrict__ cstart) {
  __shared__ uint32_t scnt[NCELL];
  __shared__ uint32_t swv[16];
  const int b = blockIdx.x;
  const int tid = threadIdx.x, lane = tid & 63, wid = tid >> 6;
  const float* __restrict__ sb = src + (size_t)b * 3 * NPTS;

  for (int i = tid; i < NCELL; i += 1024) scnt[i] = 0;
  __syncthreads();

  float px[8], py[8], pz[8];
  int pc[8];
#pragma unroll
  for (int k = 0; k < 8; ++k) {
    int p = tid + k * 1024;
    float x = sb[p], y = sb[NPTS + p], z = sb[2 * NPTS + p];
    px[k] = x; py[k] = y; pz[k] = z;
    int cx, cy, cz;
    cell_coords(x, y, z, cx, cy, cz);
    pc[k] = ((cz * GRID) + cy) * GRID + cx;
    atomicAdd(&scnt[pc[k]], 1u);
  }
  __syncthreads();

  const int i0 = tid * 4;
  uint32_t v[4], ts = 0;
#pragma unroll
  for (int k = 0; k < 4; ++k) {
    v[k] = (i0 + k < NCELL) ? scnt[i0 + k] : 0u;
    ts += v[k];
  }
  uint32_t x = ts;
#pragma unroll
  for (int off = 1; off < 64; off <<= 1) {
    uint32_t y = __shfl_up(x, off, 64);
    if (lane >= off) x += y;
  }
  if (lane == 63) swv[wid] = x;
  __syncthreads();
  uint32_t wpre = 0, bsum = 0;
  for (int w = 0; w < 16; ++w) { uint32_t s = swv[w]; bsum += s; if (w < wid) wpre += s; }
  uint32_t excl = wpre + (x - ts);
#pragma unroll
  for (int k = 0; k < 4; ++k) {
    if (i0 + k < NCELL) {
      cstart[b * (NCELL + 1) + i0 + k] = excl;
      scnt[i0 + k] = excl;
      excl += v[k];
    }
  }
  if (tid == 0) cstart[b * (NCELL + 1) + NCELL] = bsum;
  __syncthreads();

#pragma unroll
  for (int k = 0; k < 8; ++k) {
    uint32_t pos = atomicAdd(&scnt[pc[k]], 1u);
    pts[(b << 13) + pos]  = make_float4(px[k], py[k], pz[k],
                                        px[k] * px[k] + py[k] * py[k] + pz[k] * pz[k]);
    oidx[(b << 13) + pos] = (uint32_t)(tid + k * 1024);
  }
}

// ---------------- main: R17 body, phase-2 barriers wave-local ----------------
__global__ __launch_bounds__(256) void gfm_grid(const float* __restrict__ src,
                                                const float* __restrict__ tgt,
                                                const float4* __restrict__ pts,
                                                const uint32_t* __restrict__ oidx,
                                                const uint32_t* __restrict__ cstart,
                                                float* __restrict__ mean_out) {
  __shared__ uint64_t sqq[4][QSZ];
  __shared__ uint64_t stp[4][MARGIN];
  __shared__ double lsA[4][NPAIR];
  __shared__ double lsB[4][NPAIR];
  __shared__ double smed[4];
  __shared__ double ssum[4][KNN];
  __shared__ double rd2[4][MARGIN];
  __shared__ int    rid[4][MARGIN];
  __shared__ int    snbr[4][KNN];

  const int tid  = threadIdx.x;
  const int wv   = tid >> 6;
  const int lane = tid & 63;
  const int b    = blockIdx.x >> 11;
  const int n    = ((blockIdx.x & 2047) << 2) | wv;

  const float* __restrict__ sb = src + (size_t)b * 3 * NPTS;
  const float* __restrict__ tb = tgt + (size_t)b * 3 * NPTS;
  const float4* __restrict__ ppts = pts + ((size_t)b << 13);
  const uint32_t* __restrict__ poid = oidx + ((size_t)b << 13);
  const uint32_t* __restrict__ cs = cstart + (size_t)b * (NCELL + 1);

  const float xnf = sb[n], ynf = sb[NPTS + n], znf = sb[2 * NPTS + n];
  const float sqnf = xnf * xnf + ynf * ynf + znf * znf;

  int qcx, qcy, qcz;
  cell_coords(xnf, ynf, znf, qcx, qcy, qcz);
  float lox = ORG + qcx * HCELL, loy = ORG + qcy * HCELL, loz = ORG + qcz * HCELL;
  float dqx = fmaxf(fmaxf(lox - xnf, xnf - (lox + HCELL)), 0.0f);
  float dqy = fmaxf(fmaxf(loy - ynf, ynf - (loy + HCELL)), 0.0f);
  float dqz = fmaxf(fmaxf(loz - znf, znf - (loz + HCELL)), 0.0f);
  const float deltaq = sqrtf(dqx * dqx + dqy * dqy + dqz * dqz);

  if (lane < MARGIN) stp[wv][lane] = ~0ull;
  WVBAR();
  float tau_f = __builtin_inff();
  int qn = 0;          // wave-uniform
  bool boot = false;   // wave-uniform

  auto drain = [&]() {
    int tot = qn;
    if (boot) {
      if (lane < MARGIN) sqq[wv][qn + lane] = stp[wv][lane];
      tot = qn + MARGIN;
    }
    WVBAR();
    if (tot <= 64) {
      uint64_t k0 = (lane < tot) ? sqq[wv][lane] : ~0ull;
      int r0 = 0;
      for (int m = 0; m < tot; ++m) r0 += (sqq[wv][m] < k0);
      WVBAR();
      if (lane < tot && r0 < MARGIN) stp[wv][r0] = k0;
    } else {
      uint64_t k0 = (lane < tot) ? sqq[wv][lane] : ~0ull;
      uint64_t k1 = (lane + 64 < tot) ? sqq[wv][lane + 64] : ~0ull;
      int r0 = 0, r1 = 0;
      for (int m = 0; m < tot; ++m) {
        uint64_t km = sqq[wv][m];
        r0 += (km < k0);
        r1 += (km < k1);
      }
      WVBAR();
      if (lane < tot && r0 < MARGIN) stp[wv][r0] = k0;
      if (lane + 64 < tot && r1 < MARGIN) stp[wv][r1] = k1;
    }
    WVBAR();
    tau_f = __uint_as_float((uint32_t)(stp[wv][MARGIN - 1] >> 32));
    boot = true;
    qn = 0;
  };

  auto scan_range = [&](int cy, int cz, int cx0, int cx1) {
    if (cy < 0 || cy >= GRID || cz < 0 || cz >= GRID) return;
    cx0 = max(cx0, 0); cx1 = min(cx1, GRID - 1);
    if (cx0 > cx1) return;
    float bx0 = ORG + cx0 * HCELL, bx1 = ORG + (cx1 + 1) * HCELL;
    float by0 = ORG + cy * HCELL,  by1 = by0 + HCELL;
    float bz0 = ORG + cz * HCELL,  bz1 = bz0 + HCELL;
    float ddx = fmaxf(fmaxf(bx0 - xnf, xnf - bx1), 0.0f);
    float ddy = fmaxf(fmaxf(by0 - ynf, ynf - by1), 0.0f);
    float ddz = fmaxf(fmaxf(bz0 - znf, znf - bz1), 0.0f);
    float rowmin = ddx * ddx + ddy * ddy + ddz * ddz;
    if (rowmin > tau_f * 1.001f + 1e-5f) return;   // inf-safe, conservative
    uint32_t c0 = (uint32_t)(((cz * GRID) + cy) * GRID + cx0);
    uint32_t st = cs[c0];
    uint32_t en = cs[c0 + (uint32_t)(cx1 - cx0) + 1];
    for (uint32_t base = st; base < en; base += 64) {
      uint32_t pp = base + (uint32_t)lane;
      bool act = pp < en;
      float d2 = 0.0f;
      bool pred = false;
      if (act) {
        float4 c4 = ppts[pp];
        float dot = fmaf(xnf, c4.x, fmaf(ynf, c4.y, znf * c4.z));
        d2 = fmaxf(fmaf(-2.0f, dot, sqnf + c4.w), 0.0f);
        pred = d2 <= tau_f;
      }
      uint64_t m2 = __ballot(pred);
      if (m2) {
        int below = __builtin_amdgcn_mbcnt_hi((uint32_t)(m2 >> 32),
                     __builtin_amdgcn_mbcnt_lo((uint32_t)m2, 0));
        if (pred) {
          uint64_t key = ((uint64_t)__float_as_uint(d2) << 32) | (uint64_t)poid[pp];
          sqq[wv][qn + below] = key;
        }
        WVBAR();
        qn += __popcll(m2);
        if (qn >= DRAIN_AT) drain();
      }
    }
  };

  // center row FIRST (tightens tau immediately), then remaining 8 box-1 rows
  scan_range(qcy, qcz, qcx - 1, qcx + 1);
#pragma unroll
  for (int dz = -1; dz <= 1; ++dz)
#pragma unroll
    for (int dy = -1; dy <= 1; ++dy)
      if (!(dy == 0 && dz == 0))
        scan_range(qcy + dy, qcz + dz, qcx - 1, qcx + 1);

  // shells r>=2 (rare)
  for (int r = 2; r < GRID; ++r) {
    float mrg = (float)(r - 1) * HCELL - deltaq;
    if (mrg > 0.0f && mrg * mrg > tau_f * 1.0001f) break;
    for (int dz = -r; dz <= r; ++dz)
      for (int dy = -r; dy <= r; ++dy) {
        if (abs(dz) == r || abs(dy) == r) {
          scan_range(qcy + dy, qcz + dz, qcx - r, qcx + r);
        } else {
          scan_range(qcy + dy, qcz + dz, qcx - r, qcx - r);
          scan_range(qcy + dy, qcz + dz, qcx + r, qcx + r);
        }
      }
  }
  if (qn > 0) drain();

  if (lane < MARGIN) rid[wv][lane] = (int)(uint32_t)(stp[wv][lane] & 0xFFFFFFFFull);
  WVBAR();

  // ---- exact f64 re-rank of 12 candidates (wave-local barriers) ----
  const double xn = (double)xnf, yn = (double)ynf, zn = (double)znf;
  const double sqn = xn * xn + yn * yn + zn * zn;
  double myd2 = 0.0;
  int myid = 0;
  if (lane < MARGIN) {
    myid = rid[wv][lane];
    double gx = (double)sb[myid], gy = (double)sb[NPTS + myid], gz = (double)sb[2 * NPTS + myid];
    double gsq = gx * gx + gy * gy + gz * gz;
    double dot = xn * gx + yn * gy + zn * gz;
    double d2 = sqn + gsq - 2.0 * dot;
    if (d2 < 0.0) d2 = 0.0;
    myd2 = d2;
    rd2[wv][lane] = d2;
  }
  WVBAR();
  if (lane < MARGIN) {
    int rk = 0;
    for (int m = 0; m < MARGIN; ++m) {
      double dm = rd2[wv][m];
      rk += (dm < myd2) || (dm == myd2 && rid[wv][m] < myid);
    }
    if (rk < KNN) snbr[wv][rk] = myid;
  }
  WVBAR();

  // ---- phase 2 (wave-local barriers; math identical to rounds 8-17) ----
  const double txn = (double)tb[n], tyn = (double)tb[NPTS + n], tzn = (double)tb[2 * NPTS + n];
  const int p = lane;
  double loss = 0.0, reg = 0.0;
  if (p < NPAIR) {
    int g1 = snbr[wv][dCOMB_A[p]];
    int g2 = snbr[wv][dCOMB_B[p]];

    double ax = (double)sb[g1] - xn, ay = (double)sb[NPTS + g1] - yn, az = (double)sb[2 * NPTS + g1] - zn;
    double bx = (double)sb[g2] - xn, by = (double)sb[NPTS + g2] - yn, bz = (double)sb[2 * NPTS + g2] - zn;
    double cx = ay * bz - az * by;
    double cy = az * bx - ax * bz;
    double cz = ax * by - ay * bx;
    double s  = cx * cx + cy * cy + cz * cz;
    double a_s = (s > 0.0) ? 0.5 * sqrt(s) : 0.0;

    double ux = (double)tb[g1] - txn, uy = (double)tb[NPTS + g1] - tyn, uz = (double)tb[2 * NPTS + g1] - tzn;
    double vx = (double)tb[g2] - txn, vy = (double)tb[NPTS + g2] - tyn, vz = (double)tb[2 * NPTS + g2] - tzn;
    double wx = uy * vz - uz * vy;
    double wy = uz * vx - ux * vz;
    double wz = ux * vy - uy * vx;
    double t2 = wx * wx + wy * wy + wz * wz;
    double a_t = (t2 > 0.0) ? 0.5 * sqrt(t2) : 0.0;

    double ate = a_t + EPSD;
    double d   = a_s - ate;
    double numer = (EPSD * EPSD + EPSD * EPSD) + d * d;
    double denom = (EPSD + EPSD) + (a_s + ate);
    loss = numer / denom;
    reg  = sqrt(numer);
    lsA[wv][p] = loss;
  }
  WVBAR();

  if (p < NPAIR) {
    int rk = 0;
    for (int m = 0; m < NPAIR; ++m) {
      double lm = lsA[wv][m];
      rk += (lm < loss) || (lm == loss && m < p);
    }
    lsB[wv][rk] = loss;
  }
  WVBAR();
  double tot2 = 0.0;
  if (p < NPAIR) {
    tot2 = lsB[wv][p] + 0.1 * reg;
    lsA[wv][p] = tot2;
  }
  WVBAR();
  if (p < NPAIR) {
    int rk = 0;
    for (int m = 0; m < NPAIR; ++m) {
      double tm = lsA[wv][m];
      rk += (tm < tot2) || (tm == tot2 && m < p);
    }
    if (rk == (NPAIR - 1) / 2) smed[wv] = tot2;
  }
  WVBAR();
  double med = smed[wv];
  if (p < KNN) {
    double t = (tot2 > 3.0 * med) ? 0.0 : tot2;
    ssum[wv][p] = sqrt(t + EPSD);
  }
  WVBAR();
  if (lane == 0) {
    double sum = 0.0;
#pragma unroll
    for (int q = 0; q < KNN; ++q) sum += ssum[wv][q];
    mean_out[b * NPTS + n] = (float)(sum / 10.0);
  }
}

// ---------------- fallback: R11 full-scan kernels (unchanged) ----------------
__global__ __launch_bounds__(256) void pack_pts(const float* __restrict__ src,
                                                float4* __restrict__ pk) {
  int i = blockIdx.x * 256 + threadIdx.x;
  int b = i >> 13, p = i & (NPTS - 1);
  const float* sb = src + (size_t)b * 3 * NPTS;
  float x = sb[p], y = sb[NPTS + p], z = sb[2 * NPTS + p];
  pk[i] = make_float4(x, y, z, x * x + y * y + z * z);
}

template <bool PACKED>
__global__ __launch_bounds__(256) void gfm_wave(const float* __restrict__ src,
                                                const float* __restrict__ tgt,
                                                const float4* __restrict__ pk,
                                                float* __restrict__ mean_out) {
  __shared__ float4   s4[TILE];
  __shared__ uint64_t sqq[4][QSZ];
  __shared__ uint64_t stp[4][MARGIN];
  __shared__ double lsA[4][NPAIR];
  __shared__ double lsB[4][NPAIR];
  __shared__ double smed[4];
  __shared__ double ssum[4][KNN];
  __shared__ double rd2[4][MARGIN];
  __shared__ int    rid[4][MARGIN];
  __shared__ int    snbr[4][KNN];

  const int tid  = threadIdx.x;
  const int wv   = tid >> 6;
  const int lane = tid & 63;
  const int b    = blockIdx.x >> 11;
  const int n    = ((blockIdx.x & 2047) << 2) | wv;

  const float* __restrict__ sb = src + (size_t)b * 3 * NPTS;
  const float* __restrict__ tb = tgt + (size_t)b * 3 * NPTS;

  const float xnf = sb[n], ynf = sb[NPTS + n], znf = sb[2 * NPTS + n];
  const float sqnf = xnf * xnf + ynf * ynf + znf * znf;

  if (lane < MARGIN) stp[wv][lane] = ~0ull;
  WVBAR();
  float tau_f = __builtin_inff();
  int qn = 0;
  bool boot = false;

  auto drain = [&]() {
    int tot = qn;
    if (boot) {
      if (lane < MARGIN) sqq[wv][qn + lane] = stp[wv][lane];
      tot = qn + MARGIN;
    }
    WVBAR();
    if (tot <= 64) {
      uint64_t k0 = (lane < tot) ? sqq[wv][lane] : ~0ull;
      int r0 = 0;
      for (int m = 0; m < tot; ++m) r0 += (sqq[wv][m] < k0);
      WVBAR();
      if (lane < tot && r0 < MARGIN) stp[wv][r0] = k0;
    } else {
      uint64_t k0 = (lane < tot) ? sqq[wv][lane] : ~0ull;
      uint64_t k1 = (lane + 64 < tot) ? sqq[wv][lane + 64] : ~0ull;
      int r0 = 0, r1 = 0;
      for (int m = 0; m < tot; ++m) {
        uint64_t km = sqq[wv][m];
        r0 += (km < k0);
        r1 += (km < k1);
      }
      WVBAR();
      if (lane < tot && r0 < MARGIN) stp[wv][r0] = k0;
      if (lane + 64 < tot && r1 < MARGIN) stp[wv][r1] = k1;
    }
    WVBAR();
    tau_f = __uint_as_float((uint32_t)(stp[wv][MARGIN - 1] >> 32));
    boot = true;
    qn = 0;
  };

  for (int t0 = 0; t0 < NPTS; t0 += TILE) {
    __syncthreads();
    if (PACKED) {
      const float4* __restrict__ g = pk + (size_t)b * NPTS + t0;
#pragma unroll
      for (int r = 0; r < TILE / 256; ++r) {
        int i = tid + r * 256;
        s4[i] = g[i];
      }
    } else {
#pragma unroll
      for (int r = 0; r < TILE / 256; ++r) {
        int i = tid + r * 256;
        float x = sb[t0 + i], y = sb[NPTS + t0 + i], z = sb[2 * NPTS + t0 + i];
        s4[i] = make_float4(x, y, z, x * x + y * y + z * z);
      }
    }
    __syncthreads();
#pragma unroll 2
    for (int r = 0; r < TILE / 64; ++r) {
      int j = lane + (r << 6);
      float4 c = s4[j];
      float dot = fmaf(xnf, c.x, fmaf(ynf, c.y, znf * c.z));
      float d2 = fmaxf(fmaf(-2.0f, dot, sqnf + c.w), 0.0f);
      bool pred = d2 <= tau_f;
      uint64_t mask = __ballot(pred);
      if (mask) {
        uint64_t key = ((uint64_t)__float_as_uint(d2) << 32) | (uint32_t)(t0 + j);
        int below = __builtin_amdgcn_mbcnt_hi((uint32_t)(mask >> 32),
                     __builtin_amdgcn_mbcnt_lo((uint32_t)mask, 0));
        if (pred) sqq[wv][qn + below] = key;
        WVBAR();
        qn += __popcll(mask);
        if (qn >= DRAIN_AT) drain();
      }
    }
  }
  if (qn > 0) drain();

  if (lane < MARGIN) rid[wv][lane] = (int)(uint32_t)(stp[wv][lane] & 0xFFFFFFFFull);
  __syncthreads();

  const double xn = (double)xnf, yn = (double)ynf, zn = (double)znf;
  const double sqn = xn * xn + yn * yn + zn * zn;
  double myd2 = 0.0;
  int myid = 0;
  if (lane < MARGIN) {
    myid = rid[wv][lane];
    double gx = (double)sb[myid], gy = (double)sb[NPTS + myid], gz = (double)sb[2 * NPTS + myid];
    double gsq = gx * gx + gy * gy + gz * gz;
    double dot = xn * gx + yn * gy + zn * gz;
    double d2 = sqn + gsq - 2.0 * dot;
    if (d2 < 0.0) d2 = 0.0;
    myd2 = d2;
    rd2[wv][lane] = d2;
  }
  __syncthreads();
  if (lane < MARGIN) {
    int rk = 0;
    for (int m = 0; m < MARGIN; ++m) {
      double dm = rd2[wv][m];
      rk += (dm < myd2) || (dm == myd2 && rid[wv][m] < myid);
    }
    if (rk < KNN) snbr[wv][rk] = myid;
  }
  __syncthreads();

  const double txn = (double)tb[n], tyn = (double)tb[NPTS + n], tzn = (double)tb[2 * NPTS + n];
  const int p = lane;
  double loss = 0.0, reg = 0.0;
  if (p < NPAIR) {
    int g1 = snbr[wv][dCOMB_A[p]];
    int g2 = snbr[wv][dCOMB_B[p]];

    double ax = (double)sb[g1] - xn, ay = (double)sb[NPTS + g1] - yn, az = (double)sb[2 * NPTS + g1] - zn;
    double bx = (double)sb[g2] - xn, by = (double)sb[NPTS + g2] - yn, bz = (double)sb[2 * NPTS + g2] - zn;
    double cx = ay * bz - az * by;
    double cy = az * bx - ax * bz;
    double cz = ax * by - ay * bx;
    double s  = cx * cx + cy * cy + cz * cz;
    double a_s = (s > 0.0) ? 0.5 * sqrt(s) : 0.0;

    double ux = (double)tb[g1] - txn, uy = (double)tb[NPTS + g1] - tyn, uz = (double)tb[2 * NPTS + g1] - tzn;
    double vx = (double)tb[g2] - txn, vy = (double)tb[NPTS + g2] - tyn, vz = (double)tb[2 * NPTS + g2] - tzn;
    double wx = uy * vz - uz * vy;
    double wy = uz * vx - ux * vz;
    double wz = ux * vy - uy * vx;
    double t2 = wx * wx + wy * wy + wz * wz;
    double a_t = (t2 > 0.0) ? 0.5 * sqrt(t2) : 0.0;

    double ate = a_t + EPSD;
    double d   = a_s - ate;
    double numer = (EPSD * EPSD + EPSD * EPSD) + d * d;
    double denom = (EPSD + EPSD) + (a_s + ate);
    loss = numer / denom;
    reg  = sqrt(numer);
    lsA[wv][p] = loss;
  }
  __syncthreads();

  if (p < NPAIR) {
    int rk = 0;
    for (int m = 0; m < NPAIR; ++m) {
      double lm = lsA[wv][m];
      rk += (lm < loss) || (lm == loss && m < p);
    }
    lsB[wv][rk] = loss;
  }
  __syncthreads();
  double tot2 = 0.0;
  if (p < NPAIR) {
    tot2 = lsB[wv][p] + 0.1 * reg;
    lsA[wv][p] = tot2;
  }
  __syncthreads();
  if (p < NPAIR) {
    int rk = 0;
    for (int m = 0; m < NPAIR; ++m) {
      double tm = lsA[wv][m];
      rk += (tm < tot2) || (tm == tot2 && m < p);
    }
    if (rk == (NPAIR - 1) / 2) smed[wv] = tot2;
  }
  __syncthreads();
  double med = smed[wv];
  if (p < KNN) {
    double t = (tot2 > 3.0 * med) ? 0.0 : tot2;
    ssum[wv][p] = sqrt(t + EPSD);
  }
  __syncthreads();
  if (lane == 0) {
    double sum = 0.0;
#pragma unroll
    for (int q = 0; q < KNN; ++q) sum += ssum[wv][q];
    mean_out[b * NPTS + n] = (float)(sum / 10.0);
  }
}

// ---------------- finalize (unchanged) ----------------
__global__ __launch_bounds__(1024) void gfm_finalize(float* __restrict__ buf) {
  __shared__ float red[16];
  const int b = blockIdx.x;
  const int tid = threadIdx.x;
  float* __restrict__ mb = buf + b * NPTS;

  float v[8];
  float mn = 3.4e38f;
#pragma unroll
  for (int r = 0; r < 8; ++r) {
    v[r] = mb[tid + r * 1024];
    mn = fminf(mn, v[r]);
  }
#pragma unroll
  for (int s = 32; s >= 1; s >>= 1)
    mn = fminf(mn, __shfl_xor(mn, s, 64));
  if ((tid & 63) == 0) red[tid >> 6] = mn;
  __syncthreads();
  mn = red[0];
#pragma unroll
  for (int q = 1; q < 16; ++q) mn = fminf(mn, red[q]);
  __syncthreads();

#pragma unroll
  for (int r = 0; r < 8; ++r) {
    double t = (double)v[r] - (double)mn;
    double w = 2.0 / (1.0 + exp(20.0 * t));
    mb[tid + r * 1024] = (w > 0.5) ? 1.0f : 0.0f;
  }
}

extern "C" void kernel_launch(void* const* d_in, const int* in_sizes, int n_in,
                              void* d_out, int out_size, void* d_ws, size_t ws_size,
                              hipStream_t stream) {
  const float* src = (const float*)d_in[0];
  const float* tgt = (const float*)d_in[1];
  float* out = (float*)d_out;

  const size_t nP = (size_t)NBATCH * NPTS;
  const size_t sz_pts  = nP * sizeof(float4);
  const size_t sz_oidx = nP * sizeof(uint32_t);
  const size_t sz_cs   = (size_t)NBATCH * (NCELL + 1) * 4;
  const size_t need = sz_pts + sz_oidx + sz_cs;

  if (ws_size >= need) {
    char* w = (char*)d_ws;
    float4*   pts = (float4*)w;
    uint32_t* oid = (uint32_t*)(w + sz_pts);
    uint32_t* cst = (uint32_t*)(w + sz_pts + sz_oidx);

    grid_build<<<NBATCH, 1024, 0, stream>>>(src, pts, oid, cst);
    gfm_grid<<<NBATCH * NPTS / 4, 256, 0, stream>>>(src, tgt, pts, oid, cst, out);
  } else if (ws_size >= sz_pts) {
    float4* pk = (float4*)d_ws;
    pack_pts<<<(int)(nP / 256), 256, 0, stream>>>(src, pk);
    gfm_wave<true><<<NBATCH * NPTS / 4, 256, 0, stream>>>(src, tgt, pk, out);
  } else {
    gfm_wave<false><<<NBATCH * NPTS / 4, 256, 0, stream>>>(src, tgt, nullptr, out);
  }
  gfm_finalize<<<NBATCH, 1024, 0, stream>>>(out);
}

// Round 19
// 136.211 us; speedup vs baseline: 1.3387x; 1.0018x over previous
//
#include <hip/hip_runtime.h>
#include <cstdint>
#include <cstddef>

#define NPTS 8192
#define NBATCH 4
#define KNN 10
#define NPAIR 45
#define TILE 512
#define MARGIN 12
#define QSZ 128
#define DRAIN_AT 52
#define EPSD 1e-6
#define GRID 14
#define NCELL (GRID*GRID*GRID)
#define HCELL 0.7f
#define ORG (-4.9f)

#define WVBAR() __builtin_amdgcn_wave_barrier()

__device__ __constant__ int dCOMB_A[NPAIR] = {
  0,0,0,0,0,0,0,0,0, 1,1,1,1,1,1,1,1, 2,2,2,2,2,2,2,
  3,3,3,3,3,3, 4,4,4,4,4, 5,5,5,5, 6,6,6, 7,7, 8};
__device__ __constant__ int dCOMB_B[NPAIR] = {
  1,2,3,4,5,6,7,8,9, 2,3,4,5,6,7,8,9, 3,4,5,6,7,8,9,
  4,5,6,7,8,9, 5,6,7,8,9, 6,7,8,9, 7,8,9, 8,9, 9};

__device__ __forceinline__ void cell_coords(float x, float y, float z,
                                            int& cx, int& cy, int& cz) {
  cx = (int)floorf((x - ORG) * (1.0f / HCELL));
  cy = (int)floorf((y - ORG) * (1.0f / HCELL));
  cz = (int)floorf((z - ORG) * (1.0f / HCELL));
  cx = min(max(cx, 0), GRID - 1);
  cy = min(max(cy, 0), GRID - 1);
  cz = min(max(cz, 0), GRID - 1);
}

// ---------------- fused grid build: one block per batch (R15, proven) ----------------
__global__ __launch_bounds__(1024) void grid_build(const float* __restrict__ src,
                                                   float4* __restrict__ pts,
                                                   uint32_t* __restrict__ oidx,
                                                   uint32_t* __restrict__ cstart) {
  __shared__ uint32_t scnt[NCELL];
  __shared__ uint32_t swv[16];
  const int b = blockIdx.x;
  const int tid = threadIdx.x, lane = tid & 63, wid = tid >> 6;
  const float* __restrict__ sb = src + (size_t)b * 3 * NPTS;

  for (int i = tid; i < NCELL; i += 1024) scnt[i] = 0;
  __syncthreads();

  float px[8], py[8], pz[8];
  int pc[8];
#pragma unroll
  for (int k = 0; k < 8; ++k) {
    int p = tid + k * 1024;
    float x = sb[p], y = sb[NPTS + p], z = sb[2 * NPTS + p];
    px[k] = x; py[k] = y; pz[k] = z;
    int cx, cy, cz;
    cell_coords(x, y, z, cx, cy, cz);
    pc[k] = ((cz * GRID) + cy) * GRID + cx;
    atomicAdd(&scnt[pc[k]], 1u);
  }
  __syncthreads();

  const int i0 = tid * 4;
  uint32_t v[4], ts = 0;
#pragma unroll
  for (int k = 0; k < 4; ++k) {
    v[k] = (i0 + k < NCELL) ? scnt[i0 + k] : 0u;
    ts += v[k];
  }
  uint32_t x = ts;
#pragma unroll
  for (int off = 1; off < 64; off <<= 1) {
    uint32_t y = __shfl_up(x, off, 64);
    if (lane >= off) x += y;
  }
  if (lane == 63) swv[wid] = x;
  __syncthreads();
  uint32_t wpre = 0, bsum = 0;
  for (int w = 0; w < 16; ++w) { uint32_t s = swv[w]; bsum += s; if (w < wid) wpre += s; }
  uint32_t excl = wpre + (x - ts);
#pragma unroll
  for (int k = 0; k < 4; ++k) {
    if (i0 + k < NCELL) {
      cstart[b * (NCELL + 1) + i0 + k] = excl;
      scnt[i0 + k] = excl;
      excl += v[k];
    }
  }
  if (tid == 0) cstart[b * (NCELL + 1) + NCELL] = bsum;
  __syncthreads();

#pragma unroll
  for (int k = 0; k < 8; ++k) {
    uint32_t pos = atomicAdd(&scnt[pc[k]], 1u);
    pts[(b << 13) + pos]  = make_float4(px[k], py[k], pz[k],
                                        px[k] * px[k] + py[k] * py[k] + pz[k] * pz[k]);
    oidx[(b << 13) + pos] = (uint32_t)(tid + k * 1024);
  }
}

// ---------------- main: R18 body + 4-wide rank loops ----------------
__global__ __launch_bounds__(256) void gfm_grid(const float* __restrict__ src,
                                                const float* __restrict__ tgt,
                                                const float4* __restrict__ pts,
                                                const uint32_t* __restrict__ oidx,
                                                const uint32_t* __restrict__ cstart,
                                                float* __restrict__ mean_out) {
  __shared__ uint64_t sqq[4][QSZ];
  __shared__ uint64_t stp[4][MARGIN];
  __shared__ double lsA[4][NPAIR];
  __shared__ double lsB[4][NPAIR];
  __shared__ double smed[4];
  __shared__ double ssum[4][KNN];
  __shared__ double rd2[4][MARGIN];
  __shared__ int    rid[4][MARGIN];
  __shared__ int    snbr[4][KNN];

  const int tid  = threadIdx.x;
  const int wv   = tid >> 6;
  const int lane = tid & 63;
  const int b    = blockIdx.x >> 11;
  const int n    = ((blockIdx.x & 2047) << 2) | wv;

  const float* __restrict__ sb = src + (size_t)b * 3 * NPTS;
  const float* __restrict__ tb = tgt + (size_t)b * 3 * NPTS;
  const float4* __restrict__ ppts = pts + ((size_t)b << 13);
  const uint32_t* __restrict__ poid = oidx + ((size_t)b << 13);
  const uint32_t* __restrict__ cs = cstart + (size_t)b * (NCELL + 1);

  const float xnf = sb[n], ynf = sb[NPTS + n], znf = sb[2 * NPTS + n];
  const float sqnf = xnf * xnf + ynf * ynf + znf * znf;

  int qcx, qcy, qcz;
  cell_coords(xnf, ynf, znf, qcx, qcy, qcz);
  float lox = ORG + qcx * HCELL, loy = ORG + qcy * HCELL, loz = ORG + qcz * HCELL;
  float dqx = fmaxf(fmaxf(lox - xnf, xnf - (lox + HCELL)), 0.0f);
  float dqy = fmaxf(fmaxf(loy - ynf, ynf - (loy + HCELL)), 0.0f);
  float dqz = fmaxf(fmaxf(loz - znf, znf - (loz + HCELL)), 0.0f);
  const float deltaq = sqrtf(dqx * dqx + dqy * dqy + dqz * dqz);

  if (lane < MARGIN) stp[wv][lane] = ~0ull;
  WVBAR();
  float tau_f = __builtin_inff();
  int qn = 0;          // wave-uniform
  bool boot = false;   // wave-uniform

  auto drain = [&]() {
    int tot = qn;
    if (boot) {
      if (lane < MARGIN) sqq[wv][qn + lane] = stp[wv][lane];
      tot = qn + MARGIN;
    }
    WVBAR();
    if (tot <= 64) {
      uint64_t k0 = (lane < tot) ? sqq[wv][lane] : ~0ull;
      int r0 = 0;
      int m = 0;
      for (; m + 3 < tot; m += 4) {        // 4-wide: 2x ds_read_b128
        uint64_t a0 = sqq[wv][m],     a1 = sqq[wv][m + 1];
        uint64_t a2 = sqq[wv][m + 2], a3 = sqq[wv][m + 3];
        r0 += (int)(a0 < k0) + (int)(a1 < k0) + (int)(a2 < k0) + (int)(a3 < k0);
      }
      for (; m < tot; ++m) r0 += (sqq[wv][m] < k0);
      WVBAR();
      if (lane < tot && r0 < MARGIN) stp[wv][r0] = k0;
    } else {
      uint64_t k0 = (lane < tot) ? sqq[wv][lane] : ~0ull;
      uint64_t k1 = (lane + 64 < tot) ? sqq[wv][lane + 64] : ~0ull;
      int r0 = 0, r1 = 0;
      int m = 0;
      for (; m + 3 < tot; m += 4) {
        uint64_t a0 = sqq[wv][m],     a1 = sqq[wv][m + 1];
        uint64_t a2 = sqq[wv][m + 2], a3 = sqq[wv][m + 3];
        r0 += (int)(a0 < k0) + (int)(a1 < k0) + (int)(a2 < k0) + (int)(a3 < k0);
        r1 += (int)(a0 < k1) + (int)(a1 < k1) + (int)(a2 < k1) + (int)(a3 < k1);
      }
      for (; m < tot; ++m) {
        uint64_t km = sqq[wv][m];
        r0 += (km < k0);
        r1 += (km < k1);
      }
      WVBAR();
      if (lane < tot && r0 < MARGIN) stp[wv][r0] = k0;
      if (lane + 64 < tot && r1 < MARGIN) stp[wv][r1] = k1;
    }
    WVBAR();
    tau_f = __uint_as_float((uint32_t)(stp[wv][MARGIN - 1] >> 32));
    boot = true;
    qn = 0;
  };

  auto scan_range = [&](int cy, int cz, int cx0, int cx1) {
    if (cy < 0 || cy >= GRID || cz < 0 || cz >= GRID) return;
    cx0 = max(cx0, 0); cx1 = min(cx1, GRID - 1);
    if (cx0 > cx1) return;
    float bx0 = ORG + cx0 * HCELL, bx1 = ORG + (cx1 + 1) * HCELL;
    float by0 = ORG + cy * HCELL,  by1 = by0 + HCELL;
    float bz0 = ORG + cz * HCELL,  bz1 = bz0 + HCELL;
    float ddx = fmaxf(fmaxf(bx0 - xnf, xnf - bx1), 0.0f);
    float ddy = fmaxf(fmaxf(by0 - ynf, ynf - by1), 0.0f);
    float ddz = fmaxf(fmaxf(bz0 - znf, znf - bz1), 0.0f);
    float rowmin = ddx * ddx + ddy * ddy + ddz * ddz;
    if (rowmin > tau_f * 1.001f + 1e-5f) return;   // inf-safe, conservative
    uint32_t c0 = (uint32_t)(((cz * GRID) + cy) * GRID + cx0);
    uint32_t st = cs[c0];
    uint32_t en = cs[c0 + (uint32_t)(cx1 - cx0) + 1];
    for (uint32_t base = st; base < en; base += 64) {
      uint32_t pp = base + (uint32_t)lane;
      bool act = pp < en;
      float d2 = 0.0f;
      bool pred = false;
      if (act) {
        float4 c4 = ppts[pp];
        float dot = fmaf(xnf, c4.x, fmaf(ynf, c4.y, znf * c4.z));
        d2 = fmaxf(fmaf(-2.0f, dot, sqnf + c4.w), 0.0f);
        pred = d2 <= tau_f;
      }
      uint64_t m2 = __ballot(pred);
      if (m2) {
        int below = __builtin_amdgcn_mbcnt_hi((uint32_t)(m2 >> 32),
                     __builtin_amdgcn_mbcnt_lo((uint32_t)m2, 0));
        if (pred) {
          uint64_t key = ((uint64_t)__float_as_uint(d2) << 32) | (uint64_t)poid[pp];
          sqq[wv][qn + below] = key;
        }
        WVBAR();
        qn += __popcll(m2);
        if (qn >= DRAIN_AT) drain();
      }
    }
  };

  // center row FIRST (tightens tau immediately), then remaining 8 box-1 rows
  scan_range(qcy, qcz, qcx - 1, qcx + 1);
#pragma unroll
  for (int dz = -1; dz <= 1; ++dz)
#pragma unroll
    for (int dy = -1; dy <= 1; ++dy)
      if (!(dy == 0 && dz == 0))
        scan_range(qcy + dy, qcz + dz, qcx - 1, qcx + 1);

  // shells r>=2 (rare)
  for (int r = 2; r < GRID; ++r) {
    float mrg = (float)(r - 1) * HCELL - deltaq;
    if (mrg > 0.0f && mrg * mrg > tau_f * 1.0001f) break;
    for (int dz = -r; dz <= r; ++dz)
      for (int dy = -r; dy <= r; ++dy) {
        if (abs(dz) == r || abs(dy) == r) {
          scan_range(qcy + dy, qcz + dz, qcx - r, qcx + r);
        } else {
          scan_range(qcy + dy, qcz + dz, qcx - r, qcx - r);
          scan_range(qcy + dy, qcz + dz, qcx + r, qcx + r);
        }
      }
  }
  if (qn > 0) drain();

  if (lane < MARGIN) rid[wv][lane] = (int)(uint32_t)(stp[wv][lane] & 0xFFFFFFFFull);
  WVBAR();

  // ---- exact f64 re-rank of 12 candidates (wave-local barriers) ----
  const double xn = (double)xnf, yn = (double)ynf, zn = (double)znf;
  const double sqn = xn * xn + yn * yn + zn * zn;
  double myd2 = 0.0;
  int myid = 0;
  if (lane < MARGIN) {
    myid = rid[wv][lane];
    double gx = (double)sb[myid], gy = (double)sb[NPTS + myid], gz = (double)sb[2 * NPTS + myid];
    double gsq = gx * gx + gy * gy + gz * gz;
    double dot = xn * gx + yn * gy + zn * gz;
    double d2 = sqn + gsq - 2.0 * dot;
    if (d2 < 0.0) d2 = 0.0;
    myd2 = d2;
    rd2[wv][lane] = d2;
  }
  WVBAR();
  if (lane < MARGIN) {
    int rk = 0;
    for (int m = 0; m < MARGIN; ++m) {
      double dm = rd2[wv][m];
      rk += (dm < myd2) || (dm == myd2 && rid[wv][m] < myid);
    }
    if (rk < KNN) snbr[wv][rk] = myid;
  }
  WVBAR();

  // ---- phase 2 (wave-local barriers; math identical to rounds 8-18) ----
  const double txn = (double)tb[n], tyn = (double)tb[NPTS + n], tzn = (double)tb[2 * NPTS + n];
  const int p = lane;
  double loss = 0.0, reg = 0.0;
  if (p < NPAIR) {
    int g1 = snbr[wv][dCOMB_A[p]];
    int g2 = snbr[wv][dCOMB_B[p]];

    double ax = (double)sb[g1] - xn, ay = (double)sb[NPTS + g1] - yn, az = (double)sb[2 * NPTS + g1] - zn;
    double bx = (double)sb[g2] - xn, by = (double)sb[NPTS + g2] - yn, bz = (double)sb[2 * NPTS + g2] - zn;
    double cx = ay * bz - az * by;
    double cy = az * bx - ax * bz;
    double cz = ax * by - ay * bx;
    double s  = cx * cx + cy * cy + cz * cz;
    double a_s = (s > 0.0) ? 0.5 * sqrt(s) : 0.0;

    double ux = (double)tb[g1] - txn, uy = (double)tb[NPTS + g1] - tyn, uz = (double)tb[2 * NPTS + g1] - tzn;
    double vx = (double)tb[g2] - txn, vy = (double)tb[NPTS + g2] - tyn, vz = (double)tb[2 * NPTS + g2] - tzn;
    double wx = uy * vz - uz * vy;
    double wy = uz * vx - ux * vz;
    double wz = ux * vy - uy * vx;
    double t2 = wx * wx + wy * wy + wz * wz;
    double a_t = (t2 > 0.0) ? 0.5 * sqrt(t2) : 0.0;

    double ate = a_t + EPSD;
    double d   = a_s - ate;
    double numer = (EPSD * EPSD + EPSD * EPSD) + d * d;
    double denom = (EPSD + EPSD) + (a_s + ate);
    loss = numer / denom;
    reg  = sqrt(numer);
    lsA[wv][p] = loss;
  }
  WVBAR();

  if (p < NPAIR) {
    int rk = 0;
    int m = 0;
    for (; m + 3 < NPAIR; m += 4) {       // 4-wide: 2x ds_read_b128
      double l0 = lsA[wv][m],     l1 = lsA[wv][m + 1];
      double l2 = lsA[wv][m + 2], l3 = lsA[wv][m + 3];
      rk += (int)((l0 < loss) || (l0 == loss && (m     ) < p));
      rk += (int)((l1 < loss) || (l1 == loss && (m + 1) < p));
      rk += (int)((l2 < loss) || (l2 == loss && (m + 2) < p));
      rk += (int)((l3 < loss) || (l3 == loss && (m + 3) < p));
    }
    for (; m < NPAIR; ++m) {
      double lm = lsA[wv][m];
      rk += (lm < loss) || (lm == loss && m < p);
    }
    lsB[wv][rk] = loss;
  }
  WVBAR();
  double tot2 = 0.0;
  if (p < NPAIR) {
    tot2 = lsB[wv][p] + 0.1 * reg;
    lsA[wv][p] = tot2;
  }
  WVBAR();
  if (p < NPAIR) {
    int rk = 0;
    int m = 0;
    for (; m + 3 < NPAIR; m += 4) {       // 4-wide: 2x ds_read_b128
      double t0 = lsA[wv][m],     t1 = lsA[wv][m + 1];
      double t2_ = lsA[wv][m + 2], t3 = lsA[wv][m + 3];
      rk += (int)((t0  < tot2) || (t0  == tot2 && (m     ) < p));
      rk += (int)((t1  < tot2) || (t1  == tot2 && (m + 1) < p));
      rk += (int)((t2_ < tot2) || (t2_ == tot2 && (m + 2) < p));
      rk += (int)((t3  < tot2) || (t3  == tot2 && (m + 3) < p));
    }
    for (; m < NPAIR; ++m) {
      double tm = lsA[wv][m];
      rk += (tm < tot2) || (tm == tot2 && m < p);
    }
    if (rk == (NPAIR - 1) / 2) smed[wv] = tot2;
  }
  WVBAR();
  double med = smed[wv];
  if (p < KNN) {
    double t = (tot2 > 3.0 * med) ? 0.0 : tot2;
    ssum[wv][p] = sqrt(t + EPSD);
  }
  WVBAR();
  if (lane == 0) {
    double sum = 0.0;
#pragma unroll
    for (int q = 0; q < KNN; ++q) sum += ssum[wv][q];
    mean_out[b * NPTS + n] = (float)(sum / 10.0);
  }
}

// ---------------- fallback: R11 full-scan kernels (unchanged) ----------------
__global__ __launch_bounds__(256) void pack_pts(const float* __restrict__ src,
                                                float4* __restrict__ pk) {
  int i = blockIdx.x * 256 + threadIdx.x;
  int b = i >> 13, p = i & (NPTS - 1);
  const float* sb = src + (size_t)b * 3 * NPTS;
  float x = sb[p], y = sb[NPTS + p], z = sb[2 * NPTS + p];
  pk[i] = make_float4(x, y, z, x * x + y * y + z * z);
}

template <bool PACKED>
__global__ __launch_bounds__(256) void gfm_wave(const float* __restrict__ src,
                                                const float* __restrict__ tgt,
                                                const float4* __restrict__ pk,
                                                float* __restrict__ mean_out) {
  __shared__ float4   s4[TILE];
  __shared__ uint64_t sqq[4][QSZ];
  __shared__ uint64_t stp[4][MARGIN];
  __shared__ double lsA[4][NPAIR];
  __shared__ double lsB[4][NPAIR];
  __shared__ double smed[4];
  __shared__ double ssum[4][KNN];
  __shared__ double rd2[4][MARGIN];
  __shared__ int    rid[4][MARGIN];
  __shared__ int    snbr[4][KNN];

  const int tid  = threadIdx.x;
  const int wv   = tid >> 6;
  const int lane = tid & 63;
  const int b    = blockIdx.x >> 11;
  const int n    = ((blockIdx.x & 2047) << 2) | wv;

  const float* __restrict__ sb = src + (size_t)b * 3 * NPTS;
  const float* __restrict__ tb = tgt + (size_t)b * 3 * NPTS;

  const float xnf = sb[n], ynf = sb[NPTS + n], znf = sb[2 * NPTS + n];
  const float sqnf = xnf * xnf + ynf * ynf + znf * znf;

  if (lane < MARGIN) stp[wv][lane] = ~0ull;
  WVBAR();
  float tau_f = __builtin_inff();
  int qn = 0;
  bool boot = false;

  auto drain = [&]() {
    int tot = qn;
    if (boot) {
      if (lane < MARGIN) sqq[wv][qn + lane] = stp[wv][lane];
      tot = qn + MARGIN;
    }
    WVBAR();
    if (tot <= 64) {
      uint64_t k0 = (lane < tot) ? sqq[wv][lane] : ~0ull;
      int r0 = 0;
      for (int m = 0; m < tot; ++m) r0 += (sqq[wv][m] < k0);
      WVBAR();
      if (lane < tot && r0 < MARGIN) stp[wv][r0] = k0;
    } else {
      uint64_t k0 = (lane < tot) ? sqq[wv][lane] : ~0ull;
      uint64_t k1 = (lane + 64 < tot) ? sqq[wv][lane + 64] : ~0ull;
      int r0 = 0, r1 = 0;
      for (int m = 0; m < tot; ++m) {
        uint64_t km = sqq[wv][m];
        r0 += (km < k0);
        r1 += (km < k1);
      }
      WVBAR();
      if (lane < tot && r0 < MARGIN) stp[wv][r0] = k0;
      if (lane + 64 < tot && r1 < MARGIN) stp[wv][r1] = k1;
    }
    WVBAR();
    tau_f = __uint_as_float((uint32_t)(stp[wv][MARGIN - 1] >> 32));
    boot = true;
    qn = 0;
  };

  for (int t0 = 0; t0 < NPTS; t0 += TILE) {
    __syncthreads();
    if (PACKED) {
      const float4* __restrict__ g = pk + (size_t)b * NPTS + t0;
#pragma unroll
      for (int r = 0; r < TILE / 256; ++r) {
        int i = tid + r * 256;
        s4[i] = g[i];
      }
    } else {
#pragma unroll
      for (int r = 0; r < TILE / 256; ++r) {
        int i = tid + r * 256;
        float x = sb[t0 + i], y = sb[NPTS + t0 + i], z = sb[2 * NPTS + t0 + i];
        s4[i] = make_float4(x, y, z, x * x + y * y + z * z);
      }
    }
    __syncthreads();
#pragma unroll 2
    for (int r = 0; r < TILE / 64; ++r) {
      int j = lane + (r << 6);
      float4 c = s4[j];
      float dot = fmaf(xnf, c.x, fmaf(ynf, c.y, znf * c.z));
      float d2 = fmaxf(fmaf(-2.0f, dot, sqnf + c.w), 0.0f);
      bool pred = d2 <= tau_f;
      uint64_t mask = __ballot(pred);
      if (mask) {
        uint64_t key = ((uint64_t)__float_as_uint(d2) << 32) | (uint32_t)(t0 + j);
        int below = __builtin_amdgcn_mbcnt_hi((uint32_t)(mask >> 32),
                     __builtin_amdgcn_mbcnt_lo((uint32_t)mask, 0));
        if (pred) sqq[wv][qn + below] = key;
        WVBAR();
        qn += __popcll(mask);
        if (qn >= DRAIN_AT) drain();
      }
    }
  }
  if (qn > 0) drain();

  if (lane < MARGIN) rid[wv][lane] = (int)(uint32_t)(stp[wv][lane] & 0xFFFFFFFFull);
  __syncthreads();

  const double xn = (double)xnf, yn = (double)ynf, zn = (double)znf;
  const double sqn = xn * xn + yn * yn + zn * zn;
  double myd2 = 0.0;
  int myid = 0;
  if (lane < MARGIN) {
    myid = rid[wv][lane];
    double gx = (double)sb[myid], gy = (double)sb[NPTS + myid], gz = (double)sb[2 * NPTS + myid];
    double gsq = gx * gx + gy * gy + gz * gz;
    double dot = xn * gx + yn * gy + zn * gz;
    double d2 = sqn + gsq - 2.0 * dot;
    if (d2 < 0.0) d2 = 0.0;
    myd2 = d2;
    rd2[wv][lane] = d2;
  }
  __syncthreads();
  if (lane < MARGIN) {
    int rk = 0;
    for (int m = 0; m < MARGIN; ++m) {
      double dm = rd2[wv][m];
      rk += (dm < myd2) || (dm == myd2 && rid[wv][m] < myid);
    }
    if (rk < KNN) snbr[wv][rk] = myid;
  }
  __syncthreads();

  const double txn = (double)tb[n], tyn = (double)tb[NPTS + n], tzn = (double)tb[2 * NPTS + n];
  const int p = lane;
  double loss = 0.0, reg = 0.0;
  if (p < NPAIR) {
    int g1 = snbr[wv][dCOMB_A[p]];
    int g2 = snbr[wv][dCOMB_B[p]];

    double ax = (double)sb[g1] - xn, ay = (double)sb[NPTS + g1] - yn, az = (double)sb[2 * NPTS + g1] - zn;
    double bx = (double)sb[g2] - xn, by = (double)sb[NPTS + g2] - yn, bz = (double)sb[2 * NPTS + g2] - zn;
    double cx = ay * bz - az * by;
    double cy = az * bx - ax * bz;
    double cz = ax * by - ay * bx;
    double s  = cx * cx + cy * cy + cz * cz;
    double a_s = (s > 0.0) ? 0.5 * sqrt(s) : 0.0;

    double ux = (double)tb[g1] - txn, uy = (double)tb[NPTS + g1] - tyn, uz = (double)tb[2 * NPTS + g1] - tzn;
    double vx = (double)tb[g2] - txn, vy = (double)tb[NPTS + g2] - tyn, vz = (double)tb[2 * NPTS + g2] - tzn;
    double wx = uy * vz - uz * vy;
    double wy = uz * vx - ux * vz;
    double wz = ux * vy - uy * vx;
    double t2 = wx * wx + wy * wy + wz * wz;
    double a_t = (t2 > 0.0) ? 0.5 * sqrt(t2) : 0.0;

    double ate = a_t + EPSD;
    double d   = a_s - ate;
    double numer = (EPSD * EPSD + EPSD * EPSD) + d * d;
    double denom = (EPSD + EPSD) + (a_s + ate);
    loss = numer / denom;
    reg  = sqrt(numer);
    lsA[wv][p] = loss;
  }
  __syncthreads();

  if (p < NPAIR) {
    int rk = 0;
    for (int m = 0; m < NPAIR; ++m) {
      double lm = lsA[wv][m];
      rk += (lm < loss) || (lm == loss && m < p);
    }
    lsB[wv][rk] = loss;
  }
  __syncthreads();
  double tot2 = 0.0;
  if (p < NPAIR) {
    tot2 = lsB[wv][p] + 0.1 * reg;
    lsA[wv][p] = tot2;
  }
  __syncthreads();
  if (p < NPAIR) {
    int rk = 0;
    for (int m = 0; m < NPAIR; ++m) {
      double tm = lsA[wv][m];
      rk += (tm < tot2) || (tm == tot2 && m < p);
    }
    if (rk == (NPAIR - 1) / 2) smed[wv] = tot2;
  }
  __syncthreads();
  double med = smed[wv];
  if (p < KNN) {
    double t = (tot2 > 3.0 * med) ? 0.0 : tot2;
    ssum[wv][p] = sqrt(t + EPSD);
  }
  __syncthreads();
  if (lane == 0) {
    double sum = 0.0;
#pragma unroll
    for (int q = 0; q < KNN; ++q) sum += ssum[wv][q];
    mean_out[b * NPTS + n] = (float)(sum / 10.0);
  }
}

// ---------------- finalize (unchanged) ----------------
__global__ __launch_bounds__(1024) void gfm_finalize(float* __restrict__ buf) {
  __shared__ float red[16];
  const int b = blockIdx.x;
  const int tid = threadIdx.x;
  float* __restrict__ mb = buf + b * NPTS;

  float v[8];
  float mn = 3.4e38f;
#pragma unroll
  for (int r = 0; r < 8; ++r) {
    v[r] = mb[tid + r * 1024];
    mn = fminf(mn, v[r]);
  }
#pragma unroll
  for (int s = 32; s >= 1; s >>= 1)
    mn = fminf(mn, __shfl_xor(mn, s, 64));
  if ((tid & 63) == 0) red[tid >> 6] = mn;
  __syncthreads();
  mn = red[0];
#pragma unroll
  for (int q = 1; q < 16; ++q) mn = fminf(mn, red[q]);
  __syncthreads();

#pragma unroll
  for (int r = 0; r < 8; ++r) {
    double t = (double)v[r] - (double)mn;
    double w = 2.0 / (1.0 + exp(20.0 * t));
    mb[tid + r * 1024] = (w > 0.5) ? 1.0f : 0.0f;
  }
}

extern "C" void kernel_launch(void* const* d_in, const int* in_sizes, int n_in,
                              void* d_out, int out_size, void* d_ws, size_t ws_size,
                              hipStream_t stream) {
  const float* src = (const float*)d_in[0];
  const float* tgt = (const float*)d_in[1];
  float* out = (float*)d_out;

  const size_t nP = (size_t)NBATCH * NPTS;
  const size_t sz_pts  = nP * sizeof(float4);
  const size_t sz_oidx = nP * sizeof(uint32_t);
  const size_t sz_cs   = (size_t)NBATCH * (NCELL + 1) * 4;
  const size_t need = sz_pts + sz_oidx + sz_cs;

  if (ws_size >= need) {
    char* w = (char*)d_ws;
    float4*   pts = (float4*)w;
    uint32_t* oid = (uint32_t*)(w + sz_pts);
    uint32_t* cst = (uint32_t*)(w + sz_pts + sz_oidx);

    grid_build<<<NBATCH, 1024, 0, stream>>>(src, pts, oid, cst);
    gfm_grid<<<NBATCH * NPTS / 4, 256, 0, stream>>>(src, tgt, pts, oid, cst, out);
  } else if (ws_size >= sz_pts) {
    float4* pk = (float4*)d_ws;
    pack_pts<<<(int)(nP / 256), 256, 0, stream>>>(src, pk);
    gfm_wave<true><<<NBATCH * NPTS / 4, 256, 0, stream>>>(src, tgt, pk, out);
  } else {
    gfm_wave<false><<<NBATCH * NPTS / 4, 256, 0, stream>>>(src, tgt, nullptr, out);
  }
  gfm_finalize<<<NBATCH, 1024, 0, stream>>>(out);
}